// Round 8
// baseline (257.394 us; speedup 1.0000x reference)
//
#include <hip/hip_runtime.h>
#include <math.h>

// ASFF_2: N=8, C1=256, C2=512, H=64, W=64, low-res 32x32.
//  K1 down_gemm: ktT = bf16T(w_down @ input2 + b_down)  [N,34*34,128] padded
//  K2 enc_mfma: kt2 = 9-tap shifted MFMA GEMM           [N,36,1024] fp32
//  K3 softmax -> mask [N,1024,36]
//  K4 CARAFE apply -> hires bf16 [ci][p]                [N,512,4096]
//  K4b transpose -> hiresT bf16 [p][ci]
//  K5 stage-once MFMA gemm: u = w_up @ hiresT           [N,256,4096]
//  K6 fuse_weights: lw0[n][p]
//  K6b transpose_blend: fusedT = bf16(i1*lw0 + u*lw1), padded [66x66][ci]
//  K7 stage-once 9-tap MFMA conv + BN + SiLU -> out
// K5/K7: B staged once; compute loop = 2-deep A (global) + 1-deep B (LDS)
// software pipeline, unroll-4 ring buffers (static indices).

#define EPS 1e-5f
typedef unsigned short u16;
typedef __attribute__((ext_vector_type(8))) __bf16 bf16x8;
typedef __attribute__((ext_vector_type(4))) float f32x4;

__device__ inline u16 f2bf(float x) {
    union { float f; unsigned u; } v; v.f = x;
    unsigned r = v.u + 0x7FFF + ((v.u >> 16) & 1);
    return (u16)(r >> 16);
}

// ---------------- K1: fp32 tiled GEMM, bf16-transposed-padded output ----------------
__global__ __launch_bounds__(256) void down_gemm_kernel(
    const float* __restrict__ A, const float* __restrict__ B,
    const float* __restrict__ bias, u16* __restrict__ ktT)
{
    const int n = blockIdx.z;
    const float* Bn = B + (long)n * 512 * 1024;
    __shared__ __align__(16) float As[16][68];
    __shared__ __align__(16) float Bs[16][64];
    const int tid = threadIdx.x;
    const int tcol = tid & 15;
    const int trow = tid >> 4;
    const int rowBase = blockIdx.y * 64;
    const int colBase = blockIdx.x * 64;
    float acc[4][4] = {};
    for (int k0 = 0; k0 < 512; k0 += 16) {
#pragma unroll
        for (int i = 0; i < 4; ++i) {
            int idx = i * 256 + tid;
            int r = idx >> 4, cc = idx & 15;
            As[cc][r] = A[(long)(rowBase + r) * 512 + k0 + cc];
        }
#pragma unroll
        for (int i = 0; i < 4; ++i) {
            int idx = i * 256 + tid;
            int r = idx >> 6, cc = idx & 63;
            Bs[r][cc] = Bn[(long)(k0 + r) * 1024 + colBase + cc];
        }
        __syncthreads();
#pragma unroll
        for (int kk = 0; kk < 16; ++kk) {
            float4 a4 = *reinterpret_cast<const float4*>(&As[kk][trow * 4]);
            float4 b4 = *reinterpret_cast<const float4*>(&Bs[kk][tcol * 4]);
            float a[4] = {a4.x, a4.y, a4.z, a4.w};
            float b[4] = {b4.x, b4.y, b4.z, b4.w};
#pragma unroll
            for (int i = 0; i < 4; ++i)
#pragma unroll
                for (int j = 0; j < 4; ++j)
                    acc[i][j] += a[i] * b[j];
        }
        __syncthreads();
    }
    u16* Kn = ktT + (long)n * 1156 * 128;
#pragma unroll
    for (int i = 0; i < 4; ++i) {
        int ch = rowBase + trow * 4 + i;
        float bv = bias[ch];
#pragma unroll
        for (int j = 0; j < 4; ++j) {
            int p = colBase + tcol * 4 + j;
            int pr = ((p >> 5) + 1) * 34 + (p & 31) + 1;
            Kn[pr * 128 + ch] = f2bf(acc[i][j] + bv);
        }
    }
}

// ---------------- K2: encoder conv as 9-tap shifted MFMA GEMM ----------------
__global__ __launch_bounds__(64) void enc_mfma_kernel(
    const u16* __restrict__ A, const u16* __restrict__ B,
    const float* __restrict__ bias, float* __restrict__ C)
{
    const int n = blockIdx.y;
    const int lane = threadIdx.x;
    const int lr = lane & 15, lk = lane >> 4;
    const int p = blockIdx.x * 16 + lr;
    const int pr = ((p >> 5) + 1) * 34 + (p & 31) + 1;
    const u16* Bn = B + (long)n * 1156 * 128;
    const int bOff = pr * 128 + lk * 8;
    f32x4 acc[3] = {};
    for (int t = 0; t < 9; ++t) {
        const u16* At = A + t * 8192;
        const int btap = ((t / 3 - 1) * 34 + (t % 3 - 1)) * 128;
#pragma unroll
        for (int k0 = 0; k0 < 128; k0 += 32) {
            bf16x8 bf = *(const bf16x8*)(Bn + bOff + btap + k0);
#pragma unroll
            for (int mf = 0; mf < 3; ++mf) {
                bf16x8 af = *(const bf16x8*)(At + (mf * 16 + lr) * 128 + lk * 8 + k0);
                acc[mf] = __builtin_amdgcn_mfma_f32_16x16x32_bf16(af, bf, acc[mf], 0, 0, 0);
            }
        }
    }
    float* Cn = C + (long)n * 36 * 1024;
#pragma unroll
    for (int mf = 0; mf < 3; ++mf)
#pragma unroll
        for (int reg = 0; reg < 4; ++reg) {
            int co = mf * 16 + lk * 4 + reg;
            if (co < 36)
                Cn[(long)co * 1024 + p] = acc[mf][reg] + bias[co];
        }
}

// ---------------- K3: softmax over k=9 ----------------
__global__ __launch_bounds__(256) void mask_softmax_kernel(
    const float* __restrict__ kt2, float* __restrict__ mask)
{
    int gid = blockIdx.x * 256 + threadIdx.x;   // N*1024*4
    int q = gid & 3;
    int p = (gid >> 2) & 1023;
    int n = gid >> 12;
    float s[9];
    float mx = -1e30f;
#pragma unroll
    for (int k = 0; k < 9; ++k) {
        s[k] = kt2[(long)(n * 36 + k * 4 + q) * 1024 + p];
        mx = fmaxf(mx, s[k]);
    }
    float sum = 0.f;
#pragma unroll
    for (int k = 0; k < 9; ++k) { s[k] = expf(s[k] - mx); sum += s[k]; }
    float inv = 1.f / sum;
    float* mp = mask + (long)(n * 1024 + p) * 36 + q;
#pragma unroll
    for (int k = 0; k < 9; ++k) mp[k * 4] = s[k] * inv;
}

// ---------------- K4: CARAFE apply -> hires bf16 [ci][p] ----------------
__global__ __launch_bounds__(256) void carafe_kernel(
    const float* __restrict__ in2, const float* __restrict__ mask,
    u16* __restrict__ hires)
{
    int bx = blockIdx.x;            // N*32*64 : (n, h, cgroup)
    int cg = bx & 63;
    int h = (bx >> 6) & 31;
    int n = bx >> 11;
    int tid = threadIdx.x;
    int w = tid & 31;
    int cl = tid >> 5;
    int c = cg * 8 + cl;
    __shared__ float mrow[32 * 37];
    const float* mg = mask + (long)(n * 1024 + h * 32) * 36;
    for (int idx = tid; idx < 32 * 36; idx += 256) {
        int pw = idx / 36, j = idx - pw * 36;
        mrow[pw * 37 + j] = mg[idx];
    }
    __syncthreads();
    const float* ip = in2 + (long)(n * 512 + c) * 1024;
    float acc[4] = {0.f, 0.f, 0.f, 0.f};
#pragma unroll
    for (int k = 0; k < 9; ++k) {
        int dh = k / 3 - 1, dw = k % 3 - 1;
        int hh = h + dh, ww = w + dw;
        float val = (hh >= 0 && hh < 32 && ww >= 0 && ww < 32) ? ip[hh * 32 + ww] : 0.f;
#pragma unroll
        for (int q = 0; q < 4; ++q)
            acc[q] += val * mrow[w * 37 + k * 4 + q];
    }
    u16* op = hires + (long)(n * 512 + c) * 4096;
#pragma unroll
    for (int q = 0; q < 4; ++q) {
        int r1 = q >> 1, r2 = q & 1;
        op[(2 * h + r1) * 64 + 2 * w + r2] = f2bf(acc[q]);
    }
}

// ---------------- K4b: transpose hires [512][4096] -> hiresT [p][512] ----------------
__global__ __launch_bounds__(256) void transpose_kernel(
    const u16* __restrict__ src0, u16* __restrict__ dst)
{
    constexpr int C = 512, CP = 514;
    __shared__ u16 lds[32 * CP];
    const int n = blockIdx.y;
    const int p0 = blockIdx.x * 32;
    const int tid = threadIdx.x;
    {
        const int w = tid & 31;
        const int chunk = tid >> 5;
        const u16* src = src0 + (long)n * C * 4096 + p0 + w;
        for (int ci = chunk * 64; ci < chunk * 64 + 64; ++ci)
            lds[w * CP + ci] = src[(long)ci * 4096];
    }
    __syncthreads();
    const int px = tid >> 3;
    const int q = tid & 7;
    u16* drow = dst + (long)n * 4096 * C + (long)(p0 + px) * C;
    const u16* lrow = lds + px * CP;
#pragma unroll
    for (int j = 0; j < C / 16; ++j) {
        int off = j * 16 + q * 2;
        *(unsigned*)(drow + off) = *(const unsigned*)(lrow + off);
    }
}

// ---------------- K6b: fused blend + transpose-cast to padded fusedT ----------------
__global__ __launch_bounds__(256) void transpose_blend_kernel(
    const float* __restrict__ i1g, const float* __restrict__ ug,
    const float* __restrict__ lw0g, u16* __restrict__ dst)
{
    constexpr int C = 256, CP = 258;
    __shared__ u16 lds[32 * CP];
    const int n = blockIdx.y;
    const int p0 = blockIdx.x * 32;
    const int tid = threadIdx.x;
    {
        const int w = tid & 31;
        const int chunk = tid >> 5;
        const int p = p0 + w;
        const float lw = lw0g[n * 4096 + p];
        const float lw1 = 1.f - lw;
        const float* s1 = i1g + (long)n * C * 4096 + p;
        const float* s2 = ug + (long)n * C * 4096 + p;
        for (int ci = chunk * 32; ci < chunk * 32 + 32; ++ci)
            lds[w * CP + ci] = f2bf(s1[(long)ci * 4096] * lw + s2[(long)ci * 4096] * lw1);
    }
    __syncthreads();
    const int px = tid >> 3;
    const int q = tid & 7;
    const int p = p0 + px;
    long prow = (long)((p >> 6) + 1) * 66 + (p & 63) + 1;
    u16* drow = dst + (long)n * 4356 * C + prow * C;
    const u16* lrow = lds + px * CP;
#pragma unroll
    for (int j = 0; j < C / 16; ++j) {
        int off = j * 16 + q * 2;
        *(unsigned*)(drow + off) = *(const unsigned*)(lrow + off);
    }
}

// ---------------- K5/K7: stage-once MFMA shifted-GEMM, pipelined ----------------
// Grid (32,1,8): 256 blocks = 1/CU. 512 thr = 8 waves (4M x 2N), wave tile 64x64,
// M=256 full per block. Whole B region staged once via global_load_lds; compute
// loop: A (global, L2-hot weights) prefetched 2 steps ahead (ring-4), B (LDS)
// 1 step ahead (ring-2); unroll-4 keeps all ring indices static.
template<int KC, int NT, bool PADDED>
__global__ __launch_bounds__(512, 2) void mfma_stage_once_kernel(
    const u16* __restrict__ A,      // [NT][256][KC] bf16
    const u16* __restrict__ B,      // per image [rows][KC] bf16
    const float* __restrict__ scale, const float* __restrict__ shift,
    float* __restrict__ C, long strideB, long strideC, int silu)
{
    constexpr int RROWS = PADDED ? 264 : 128;   // 4 padded image rows x 66 | 128 cols
    constexpr int ROWU  = KC / 8;               // 16B units per row
    constexpr int TOT16 = RROWS * ROWU;
    constexpr int NK    = KC / 32;
    constexpr int LOGNK = (NK == 8) ? 3 : 4;
    constexpr int S     = NT * NK;              // 72 | 16 (divisible by 4)
    __shared__ __align__(16) u16 lds[RROWS * KC];
    const int n = blockIdx.z;
    const u16* Bn = B + (long)n * strideB;
    float* Cn = C + (long)n * strideC;
    const int tid = threadIdx.x;
    const int lane = tid & 63;
    const int wid = tid >> 6;                   // 0..7
    const int mw = wid >> 1, nw = wid & 1;      // 4M x 2N
    const int lr = lane & 15, lk = lane >> 4;
    const int colBase = blockIdx.x * 128;
    const int g0 = PADDED ? (colBase >> 6) * 66 : colBase;

    long aBase[4];
#pragma unroll
    for (int mf = 0; mf < 4; ++mf)
        aBase[mf] = (long)(mw * 64 + mf * 16 + lr) * KC + lk * 8;

    // ---- stage entire B region ----
    for (int f = tid; f < TOT16; f += 512) {
        int r = f >> (LOGNK + 2);               // f / ROWU
        int u = f & (ROWU - 1);
        const u16* gsrc = Bn + (long)(g0 + r) * KC + ((u ^ (r & 7)) << 3);
        __builtin_amdgcn_global_load_lds(
            (const __attribute__((address_space(1))) void*)gsrc,
            (__attribute__((address_space(3))) void*)(lds + f * 8), 16, 0, 0);
    }

    f32x4 acc[4][4] = {};
    bf16x8 af[4][4], bf[2][4];
    // A prologue: s=0 (t0,k0) and s=1 (t = 1>>LOGNK = 0, k=1)
#pragma unroll
    for (int mf = 0; mf < 4; ++mf) {
        af[0][mf] = *(const bf16x8*)(A + aBase[mf]);
        af[1][mf] = *(const bf16x8*)(A + aBase[mf] + 32);
    }
    __syncthreads();                            // staging drain (once)
    {                                           // B frags for s=0
        int rbase;
        if (PADDED) rbase = nw * 66 + lr;       // t=0: dh=-1,dw=-1
        else        rbase = nw * 64 + lr;
        const int swz = rbase & 7;
#pragma unroll
        for (int nf = 0; nf < 4; ++nf)
            bf[0][nf] = *(const bf16x8*)(lds + (rbase + nf * 16) * KC + ((lk ^ swz) << 3));
    }

#pragma unroll 4
    for (int s = 0; s < S; ++s) {
        const int cur = s & 3;
        const int curb = s & 1;
        if (s + 2 < S) {                        // A prefetch, depth 2
            const int s2 = s + 2;
            const int t2 = s2 >> LOGNK;
            const int k2 = s2 & (NK - 1);
            const u16* At = A + (long)t2 * 256 * KC + (k2 << 5);
#pragma unroll
            for (int mf = 0; mf < 4; ++mf)
                af[(s + 2) & 3][mf] = *(const bf16x8*)(At + aBase[mf]);
        }
        if (s + 1 < S) {                        // B prefetch, depth 1 (LDS)
            const int s1 = s + 1;
            const int t1 = s1 >> LOGNK;
            const int k1 = s1 & (NK - 1);
            int rbase;
            if (PADDED) {
                int dh = t1 / 3 - 1, dw = t1 - (t1 / 3) * 3 - 1;
                rbase = (nw + dh + 1) * 66 + dw + 1 + lr;
            } else {
                rbase = nw * 64 + lr;
            }
            const int swz = rbase & 7;
            const int ub = k1 << 2;
#pragma unroll
            for (int nf = 0; nf < 4; ++nf)
                bf[(s + 1) & 1][nf] = *(const bf16x8*)(lds + (rbase + nf * 16) * KC +
                                                       (((ub + lk) ^ swz) << 3));
        }
#pragma unroll
        for (int mf = 0; mf < 4; ++mf)
#pragma unroll
            for (int nf = 0; nf < 4; ++nf)
                acc[mf][nf] = __builtin_amdgcn_mfma_f32_16x16x32_bf16(
                    af[cur][mf], bf[curb][nf], acc[mf][nf], 0, 0, 0);
    }

#pragma unroll
    for (int mf = 0; mf < 4; ++mf) {
#pragma unroll
        for (int reg = 0; reg < 4; ++reg) {
            int co = mw * 64 + mf * 16 + lk * 4 + reg;
            float sc = scale[co], sh = shift[co];
#pragma unroll
            for (int nf = 0; nf < 4; ++nf) {
                int col = colBase + nw * 64 + nf * 16 + lr;
                float y = acc[mf][nf][reg] * sc + sh;
                if (silu) y = y / (1.f + expf(-y));
                Cn[(long)co * 4096 + col] = y;
            }
        }
    }
}

// ---------------- K6: level weights (softmax over 2) -> lw0[n][p] ----------------
__global__ __launch_bounds__(256) void fuse_weights_kernel(
    const float* __restrict__ input1, const float* __restrict__ u,
    const float* __restrict__ w_l1, const float* __restrict__ bn_l1,
    const float* __restrict__ w_l2, const float* __restrict__ bn_l2,
    const float* __restrict__ w_wl, const float* __restrict__ b_wl,
    float* __restrict__ lw0g)
{
    int bx = blockIdx.x;            // 8 * 64
    int n = bx >> 6;
    int p0 = (bx & 63) * 64;
    int tid = threadIdx.x;
    int pos = tid & 63;
    int chunk = tid >> 6;
    int p = p0 + pos;
    const float* i1 = input1 + (long)n * 256 * 4096;
    const float* i2 = u + (long)n * 256 * 4096;
    float s1[8] = {}, s2[8] = {};
    for (int ci = chunk * 64; ci < chunk * 64 + 64; ++ci) {
        float x1 = i1[(long)ci * 4096 + p];
        float x2 = i2[(long)ci * 4096 + p];
#pragma unroll
        for (int j = 0; j < 8; ++j) {
            s1[j] += w_l1[j * 256 + ci] * x1;
            s2[j] += w_l2[j * 256 + ci] * x2;
        }
    }
    __shared__ float red[4][64][16];
#pragma unroll
    for (int j = 0; j < 8; ++j) { red[chunk][pos][j] = s1[j]; red[chunk][pos][8 + j] = s2[j]; }
    __syncthreads();
    if (tid < 64) {
        float v[16];
#pragma unroll
        for (int j = 0; j < 16; ++j)
            v[j] = red[0][tid][j] + red[1][tid][j] + red[2][tid][j] + red[3][tid][j];
        float z0 = b_wl[0], z1 = b_wl[1];
#pragma unroll
        for (int j = 0; j < 8; ++j) {
            float g = bn_l1[j], b = bn_l1[8 + j], m = bn_l1[16 + j], va = bn_l1[24 + j];
            float y = (v[j] - m) * (g * rsqrtf(va + EPS)) + b;
            float sv = y / (1.f + expf(-y));
            z0 += w_wl[j] * sv;
            z1 += w_wl[16 + j] * sv;
            g = bn_l2[j]; b = bn_l2[8 + j]; m = bn_l2[16 + j]; va = bn_l2[24 + j];
            y = (v[8 + j] - m) * (g * rsqrtf(va + EPS)) + b;
            sv = y / (1.f + expf(-y));
            z0 += w_wl[8 + j] * sv;
            z1 += w_wl[24 + j] * sv;
        }
        lw0g[n * 4096 + p0 + tid] = 1.f / (1.f + expf(z1 - z0));
    }
}

// ---------------- prep kernels ----------------
__global__ __launch_bounds__(256) void prep_w_kernel(
    const float* __restrict__ w_conv, const float* __restrict__ w_up,
    const float* __restrict__ w_enc,
    u16* __restrict__ wT, u16* __restrict__ wupT, u16* __restrict__ wencT)
{
    int gid = blockIdx.x * 256 + threadIdx.x;
    if (gid < 589824) {             // wT[t][co][ci] = w_conv[co][ci][t]
        int t = gid >> 16;
        int co = (gid >> 8) & 255;
        int ci = gid & 255;
        wT[gid] = f2bf(w_conv[(co * 256 + ci) * 9 + t]);
    }
    if (gid < 131072) wupT[gid] = f2bf(w_up[gid]);
    if (gid < 73728) {              // wencT[t][co<64][ci] (zeros co>=36)
        int t = gid >> 13;
        int co = (gid >> 7) & 63;
        int ci = gid & 127;
        wencT[gid] = (co < 36) ? f2bf(w_enc[(co * 128 + ci) * 9 + t]) : (u16)0;
    }
}

__global__ void prep_bn_kernel(const float* __restrict__ bn_conv,
                               const float* __restrict__ b_up, float* __restrict__ bnp)
{
    int i = threadIdx.x;            // 256
    float g = bn_conv[i], b = bn_conv[256 + i], m = bn_conv[512 + i], v = bn_conv[768 + i];
    float sc = g * rsqrtf(v + EPS);
    bnp[i] = sc;
    bnp[256 + i] = b - m * sc;
    bnp[512 + i] = 1.f;
    bnp[768 + i] = b_up[i];
}

extern "C" void kernel_launch(void* const* d_in, const int* in_sizes, int n_in,
                              void* d_out, int out_size, void* d_ws, size_t ws_size,
                              hipStream_t stream)
{
    const float* input1 = (const float*)d_in[0];
    const float* input2 = (const float*)d_in[1];
    const float* w_down = (const float*)d_in[2];
    const float* b_down = (const float*)d_in[3];
    const float* w_enc  = (const float*)d_in[4];
    const float* b_enc  = (const float*)d_in[5];
    const float* w_up   = (const float*)d_in[6];
    const float* b_up   = (const float*)d_in[7];
    const float* w_l1   = (const float*)d_in[8];
    const float* bn_l1  = (const float*)d_in[9];
    const float* w_l2   = (const float*)d_in[10];
    const float* bn_l2  = (const float*)d_in[11];
    const float* w_wl   = (const float*)d_in[12];
    const float* b_wl   = (const float*)d_in[13];
    const float* w_conv = (const float*)d_in[14];
    const float* bn_conv= (const float*)d_in[15];
    float* out = (float*)d_out;

    // workspace layout (float units). ~108 MB total.
    float* ws     = (float*)d_ws;
    float* ktTf   = ws;                      //   591,872 f : ktT bf16 [n][1156][128]
    float* wencTf = ktTf + 591872;           //    36,864 f : wencT bf16 [9][64][128]
    float* kt2    = wencTf + 36864;          //   294,912 f
    float* maskb  = kt2 + 294912;            //   294,912 f
    float* u      = maskb + 294912;          // 8,388,608 f
    float* hireb  = u + 8388608;             // 8,388,608 f : hires bf16 [ci][p]
    float* btb    = hireb + 8388608;         // 8,388,608 f : hiresT / fusedT bf16
    float* wTf    = btb + 8388608;           //   294,912 f
    float* wupTf  = wTf + 294912;            //    65,536 f
    float* bnp    = wupTf + 65536;           //     1,024 f
    float* lw0g   = bnp + 1024;              //    32,768 f : lw0 [8][4096]
    u16* ktT      = (u16*)ktTf;
    u16* wencT    = (u16*)wencTf;
    u16* hires_bf = (u16*)hireb;
    u16* bt       = (u16*)btb;
    u16* wT       = (u16*)wTf;
    u16* wupT     = (u16*)wupTf;

    // prep (independent of data pipeline)
    prep_w_kernel<<<dim3(2304), 256, 0, stream>>>(w_conv, w_up, w_enc, wT, wupT, wencT);
    prep_bn_kernel<<<dim3(1), 256, 0, stream>>>(bn_conv, b_up, bnp);

    // K1: ktT = bf16T(w_down @ input2 + b_down), padded 34x34 grid
    hipMemsetAsync(ktT, 0, 8L * 1156 * 128 * 2, stream);
    down_gemm_kernel<<<dim3(16, 2, 8), 256, 0, stream>>>(w_down, input2, b_down, ktT);
    // K2: kt2 = 9-tap shifted MFMA GEMM
    enc_mfma_kernel<<<dim3(64, 8), 64, 0, stream>>>(wencT, ktT, b_enc, kt2);
    // K3
    mask_softmax_kernel<<<dim3(128), 256, 0, stream>>>(kt2, maskb);
    // K4: CARAFE -> hires bf16 [ci][p]
    carafe_kernel<<<dim3(16384), 256, 0, stream>>>(input2, maskb, hires_bf);
    // K4b: transpose -> hiresT bf16 [p][512]
    transpose_kernel<<<dim3(128, 8), 256, 0, stream>>>(hires_bf, bt);
    // K5: u = w_up @ hiresT + b_up (stage-once MFMA, pipelined)
    mfma_stage_once_kernel<512, 1, false><<<dim3(32, 1, 8), 512, 0, stream>>>(
        wupT, bt, bnp + 512, bnp + 768, u, 4096L * 512, 256L * 4096, 0);
    // K6: level weights -> lw0
    fuse_weights_kernel<<<dim3(512), 256, 0, stream>>>(
        input1, u, w_l1, bn_l1, w_l2, bn_l2, w_wl, b_wl, lw0g);
    // zero fusedT borders, then blend+transpose into bt
    hipMemsetAsync(bt, 0, 8L * 4356 * 256 * 2, stream);
    transpose_blend_kernel<<<dim3(128, 8), 256, 0, stream>>>(input1, u, lw0g, bt);
    // K7: final conv (stage-once 9-tap MFMA, pipelined) + BN + SiLU
    mfma_stage_once_kernel<256, 9, true><<<dim3(32, 1, 8), 512, 0, stream>>>(
        wT, bt, bnp, bnp + 256, out, 4356L * 256, 256L * 4096, 1);
}

// Round 9
// 252.911 us; speedup vs baseline: 1.0177x; 1.0177x over previous
//
#include <hip/hip_runtime.h>
#include <math.h>

// ASFF_2: N=8, C1=256, C2=512, H=64, W=64, low-res 32x32.
//  K1 down_gemm: ktT = bf16T(w_down @ input2 + b_down)  [N,34*34,128] padded
//  K2 enc_mfma: kt2 = 9-tap shifted MFMA GEMM           [N,36,1024] fp32
//  K3 softmax -> mask [N,1024,36]
//  K4 CARAFE apply -> hires bf16 [ci][p]                [N,512,4096]
//  K4b transpose -> hiresT bf16 [p][ci]
//  K5' up_fuse MEGA: u = w_up @ hiresT (MFMA) ; v1/v2 level-attention
//      reduction in-block ; lw0 softmax ; fusedT bf16 write  [66x66 grid][ci]
//  K7 stage-once 9-tap MFMA conv + BN + SiLU -> out
// u never hits memory; fuse_weights/transpose_blend/17.8MB-memset eliminated.

#define EPS 1e-5f
typedef unsigned short u16;
typedef __attribute__((ext_vector_type(8))) __bf16 bf16x8;
typedef __attribute__((ext_vector_type(4))) float f32x4;

__device__ inline u16 f2bf(float x) {
    union { float f; unsigned u; } v; v.f = x;
    unsigned r = v.u + 0x7FFF + ((v.u >> 16) & 1);
    return (u16)(r >> 16);
}

// ---------------- K1: fp32 tiled GEMM, bf16-transposed-padded output ----------------
__global__ __launch_bounds__(256) void down_gemm_kernel(
    const float* __restrict__ A, const float* __restrict__ B,
    const float* __restrict__ bias, u16* __restrict__ ktT)
{
    const int n = blockIdx.z;
    const float* Bn = B + (long)n * 512 * 1024;
    __shared__ __align__(16) float As[16][68];
    __shared__ __align__(16) float Bs[16][64];
    const int tid = threadIdx.x;
    const int tcol = tid & 15;
    const int trow = tid >> 4;
    const int rowBase = blockIdx.y * 64;
    const int colBase = blockIdx.x * 64;
    float acc[4][4] = {};
    for (int k0 = 0; k0 < 512; k0 += 16) {
#pragma unroll
        for (int i = 0; i < 4; ++i) {
            int idx = i * 256 + tid;
            int r = idx >> 4, cc = idx & 15;
            As[cc][r] = A[(long)(rowBase + r) * 512 + k0 + cc];
        }
#pragma unroll
        for (int i = 0; i < 4; ++i) {
            int idx = i * 256 + tid;
            int r = idx >> 6, cc = idx & 63;
            Bs[r][cc] = Bn[(long)(k0 + r) * 1024 + colBase + cc];
        }
        __syncthreads();
#pragma unroll
        for (int kk = 0; kk < 16; ++kk) {
            float4 a4 = *reinterpret_cast<const float4*>(&As[kk][trow * 4]);
            float4 b4 = *reinterpret_cast<const float4*>(&Bs[kk][tcol * 4]);
            float a[4] = {a4.x, a4.y, a4.z, a4.w};
            float b[4] = {b4.x, b4.y, b4.z, b4.w};
#pragma unroll
            for (int i = 0; i < 4; ++i)
#pragma unroll
                for (int j = 0; j < 4; ++j)
                    acc[i][j] += a[i] * b[j];
        }
        __syncthreads();
    }
    u16* Kn = ktT + (long)n * 1156 * 128;
#pragma unroll
    for (int i = 0; i < 4; ++i) {
        int ch = rowBase + trow * 4 + i;
        float bv = bias[ch];
#pragma unroll
        for (int j = 0; j < 4; ++j) {
            int p = colBase + tcol * 4 + j;
            int pr = ((p >> 5) + 1) * 34 + (p & 31) + 1;
            Kn[pr * 128 + ch] = f2bf(acc[i][j] + bv);
        }
    }
}

// ---------------- K2: encoder conv as 9-tap shifted MFMA GEMM ----------------
__global__ __launch_bounds__(64) void enc_mfma_kernel(
    const u16* __restrict__ A, const u16* __restrict__ B,
    const float* __restrict__ bias, float* __restrict__ C)
{
    const int n = blockIdx.y;
    const int lane = threadIdx.x;
    const int lr = lane & 15, lk = lane >> 4;
    const int p = blockIdx.x * 16 + lr;
    const int pr = ((p >> 5) + 1) * 34 + (p & 31) + 1;
    const u16* Bn = B + (long)n * 1156 * 128;
    const int bOff = pr * 128 + lk * 8;
    f32x4 acc[3] = {};
    for (int t = 0; t < 9; ++t) {
        const u16* At = A + t * 8192;
        const int btap = ((t / 3 - 1) * 34 + (t % 3 - 1)) * 128;
#pragma unroll
        for (int k0 = 0; k0 < 128; k0 += 32) {
            bf16x8 bf = *(const bf16x8*)(Bn + bOff + btap + k0);
#pragma unroll
            for (int mf = 0; mf < 3; ++mf) {
                bf16x8 af = *(const bf16x8*)(At + (mf * 16 + lr) * 128 + lk * 8 + k0);
                acc[mf] = __builtin_amdgcn_mfma_f32_16x16x32_bf16(af, bf, acc[mf], 0, 0, 0);
            }
        }
    }
    float* Cn = C + (long)n * 36 * 1024;
#pragma unroll
    for (int mf = 0; mf < 3; ++mf)
#pragma unroll
        for (int reg = 0; reg < 4; ++reg) {
            int co = mf * 16 + lk * 4 + reg;
            if (co < 36)
                Cn[(long)co * 1024 + p] = acc[mf][reg] + bias[co];
        }
}

// ---------------- K3: softmax over k=9 ----------------
__global__ __launch_bounds__(256) void mask_softmax_kernel(
    const float* __restrict__ kt2, float* __restrict__ mask)
{
    int gid = blockIdx.x * 256 + threadIdx.x;   // N*1024*4
    int q = gid & 3;
    int p = (gid >> 2) & 1023;
    int n = gid >> 12;
    float s[9];
    float mx = -1e30f;
#pragma unroll
    for (int k = 0; k < 9; ++k) {
        s[k] = kt2[(long)(n * 36 + k * 4 + q) * 1024 + p];
        mx = fmaxf(mx, s[k]);
    }
    float sum = 0.f;
#pragma unroll
    for (int k = 0; k < 9; ++k) { s[k] = expf(s[k] - mx); sum += s[k]; }
    float inv = 1.f / sum;
    float* mp = mask + (long)(n * 1024 + p) * 36 + q;
#pragma unroll
    for (int k = 0; k < 9; ++k) mp[k * 4] = s[k] * inv;
}

// ---------------- K4: CARAFE apply -> hires bf16 [ci][p] ----------------
__global__ __launch_bounds__(256) void carafe_kernel(
    const float* __restrict__ in2, const float* __restrict__ mask,
    u16* __restrict__ hires)
{
    int bx = blockIdx.x;            // N*32*64 : (n, h, cgroup)
    int cg = bx & 63;
    int h = (bx >> 6) & 31;
    int n = bx >> 11;
    int tid = threadIdx.x;
    int w = tid & 31;
    int cl = tid >> 5;
    int c = cg * 8 + cl;
    __shared__ float mrow[32 * 37];
    const float* mg = mask + (long)(n * 1024 + h * 32) * 36;
    for (int idx = tid; idx < 32 * 36; idx += 256) {
        int pw = idx / 36, j = idx - pw * 36;
        mrow[pw * 37 + j] = mg[idx];
    }
    __syncthreads();
    const float* ip = in2 + (long)(n * 512 + c) * 1024;
    float acc[4] = {0.f, 0.f, 0.f, 0.f};
#pragma unroll
    for (int k = 0; k < 9; ++k) {
        int dh = k / 3 - 1, dw = k % 3 - 1;
        int hh = h + dh, ww = w + dw;
        float val = (hh >= 0 && hh < 32 && ww >= 0 && ww < 32) ? ip[hh * 32 + ww] : 0.f;
#pragma unroll
        for (int q = 0; q < 4; ++q)
            acc[q] += val * mrow[w * 37 + k * 4 + q];
    }
    u16* op = hires + (long)(n * 512 + c) * 4096;
#pragma unroll
    for (int q = 0; q < 4; ++q) {
        int r1 = q >> 1, r2 = q & 1;
        op[(2 * h + r1) * 64 + 2 * w + r2] = f2bf(acc[q]);
    }
}

// ---------------- K4b: transpose hires [512][4096] -> hiresT [p][512] ----------------
__global__ __launch_bounds__(256) void transpose_kernel(
    const u16* __restrict__ src0, u16* __restrict__ dst)
{
    constexpr int C = 512, CP = 514;
    __shared__ u16 lds[32 * CP];
    const int n = blockIdx.y;
    const int p0 = blockIdx.x * 32;
    const int tid = threadIdx.x;
    {
        const int w = tid & 31;
        const int chunk = tid >> 5;
        const u16* src = src0 + (long)n * C * 4096 + p0 + w;
        for (int ci = chunk * 64; ci < chunk * 64 + 64; ++ci)
            lds[w * CP + ci] = src[(long)ci * 4096];
    }
    __syncthreads();
    const int px = tid >> 3;
    const int q = tid & 7;
    u16* drow = dst + (long)n * 4096 * C + (long)(p0 + px) * C;
    const u16* lrow = lds + px * CP;
#pragma unroll
    for (int j = 0; j < C / 16; ++j) {
        int off = j * 16 + q * 2;
        *(unsigned*)(drow + off) = *(const unsigned*)(lrow + off);
    }
}

// ---------------- border_zero: zero the 66x66 pad ring of fusedT ----------------
__global__ __launch_bounds__(256) void border_zero_kernel(u16* __restrict__ ftb)
{
    int gid = blockIdx.x * 256 + threadIdx.x;   // 8 * 260 * 32 uint4
    if (gid >= 8 * 260 * 32) return;
    int n = gid / (260 * 32);
    int rem = gid - n * (260 * 32);
    int r = rem >> 5;
    int i = rem & 31;
    int h, w;
    if (r < 66)       { h = 0;  w = r; }
    else if (r < 132) { h = 65; w = r - 66; }
    else { int j = r - 132; h = 1 + (j >> 1); w = (j & 1) * 65; }
    long prow = (long)h * 66 + w;
    uint4* dst = (uint4*)(ftb + (long)n * 4356 * 256 + prow * 256) + i;
    *dst = make_uint4(0, 0, 0, 0);
}

// ---------------- K5': up-conv GEMM + level-attention fuse -> fusedT bf16 ----------------
// Grid (32,1,8), 512 thr = 8 waves (4M x 2N), wave tile 64x64, M=256 full.
// Phase 1: stage hiresT stripe (131 KB) via global_load_lds, MFMA u = w_up @ B.
// Phase 2: v1/v2 partials in-reg, LDS tree-reduce (LDS reused), lw0 softmax.
// Phase 3: blend with input1, bf16 rows in LDS, coalesced fusedT write.
__global__ __launch_bounds__(512, 2) void up_fuse_kernel(
    const u16* __restrict__ A,      // wupT [256][512] bf16
    const u16* __restrict__ B,      // hiresT [n][4096][512] bf16
    const float* __restrict__ input1,
    const float* __restrict__ bnp,  // +768 = b_up
    const float* __restrict__ wlT,  // [256][16] f32: j<8 w_l1[j][co], j>=8 w_l2[j-8][co]
    const float* __restrict__ bn_l1, const float* __restrict__ bn_l2,
    const float* __restrict__ w_wl, const float* __restrict__ b_wl,
    u16* __restrict__ fusedT)
{
    constexpr int KC = 512, TOT16 = 128 * 64, S = 16;
    __shared__ __align__(16) u16 lds[128 * KC];     // 131 KB
    const int n = blockIdx.z;
    const u16* Bn = B + (long)n * 4096 * 512;
    const int tid = threadIdx.x;
    const int lane = tid & 63;
    const int wid = tid >> 6;
    const int mw = wid >> 1, nw = wid & 1;          // 4M x 2N
    const int lr = lane & 15, lk = lane >> 4;
    const int colBase = blockIdx.x * 128;

    long aBase[4];
#pragma unroll
    for (int mf = 0; mf < 4; ++mf)
        aBase[mf] = (long)(mw * 64 + mf * 16 + lr) * KC + lk * 8;

    // ---- stage B stripe (swizzled source, linear LDS dest) ----
    for (int f = tid; f < TOT16; f += 512) {
        int r = f >> 6;
        int u = f & 63;
        const u16* gsrc = Bn + (long)(colBase + r) * KC + ((u ^ (r & 7)) << 3);
        __builtin_amdgcn_global_load_lds(
            (const __attribute__((address_space(1))) void*)gsrc,
            (__attribute__((address_space(3))) void*)(lds + f * 8), 16, 0, 0);
    }

    f32x4 acc[4][4] = {};
    bf16x8 af[2][4], bfr[2][4];
#pragma unroll
    for (int mf = 0; mf < 4; ++mf)
        af[0][mf] = *(const bf16x8*)(A + aBase[mf]);
    __syncthreads();                                // staging drain
    const int rbase = nw * 64 + lr;
    const int swz = rbase & 7;
#pragma unroll
    for (int nf = 0; nf < 4; ++nf)
        bfr[0][nf] = *(const bf16x8*)(lds + (rbase + nf * 16) * KC + ((lk ^ swz) << 3));

#pragma unroll
    for (int s = 0; s < S; ++s) {
        const int cur = s & 1;
        if (s + 1 < S) {
            const int k1 = s + 1;
            const u16* At = A + (k1 << 5);
#pragma unroll
            for (int mf = 0; mf < 4; ++mf)
                af[cur ^ 1][mf] = *(const bf16x8*)(At + aBase[mf]);
            const int ub = k1 << 2;
#pragma unroll
            for (int nf = 0; nf < 4; ++nf)
                bfr[cur ^ 1][nf] = *(const bf16x8*)(lds + (rbase + nf * 16) * KC +
                                                    (((ub + lk) ^ swz) << 3));
        }
#pragma unroll
        for (int mf = 0; mf < 4; ++mf)
#pragma unroll
            for (int nf = 0; nf < 4; ++nf)
                acc[mf][nf] = __builtin_amdgcn_mfma_f32_16x16x32_bf16(
                    af[cur][mf], bfr[cur][nf], acc[mf][nf], 0, 0, 0);
    }
    __syncthreads();                                // all LDS reads done; LDS reusable

    // ---- phase 2: level-attention partials + reduction ----
    float bup[4][4];
#pragma unroll
    for (int mf = 0; mf < 4; ++mf)
#pragma unroll
        for (int reg = 0; reg < 4; ++reg)
            bup[mf][reg] = bnp[768 + mw * 64 + mf * 16 + lk * 4 + reg];

    const float* in1p = input1 + (long)n * 256 * 4096 + colBase;
    float p1[8][4] = {}, p2[8][4] = {};
#pragma unroll
    for (int mf = 0; mf < 4; ++mf) {
#pragma unroll
        for (int reg = 0; reg < 4; ++reg) {
            const int co = mw * 64 + mf * 16 + lk * 4 + reg;
            const float* wl = wlT + co * 16;
            float w16[16];
#pragma unroll
            for (int q4 = 0; q4 < 4; ++q4)
                *(float4*)(w16 + q4 * 4) = *(const float4*)(wl + q4 * 4);
#pragma unroll
            for (int nf = 0; nf < 4; ++nf) {
                const int pl = nw * 64 + nf * 16 + lr;
                float iv = in1p[(long)co * 4096 + pl];
                float uv = acc[mf][nf][reg] + bup[mf][reg];
#pragma unroll
                for (int j = 0; j < 8; ++j) {
                    p1[j][nf] += w16[j] * iv;
                    p2[j][nf] += w16[8 + j] * uv;
                }
            }
        }
    }
    float* redF = (float*)lds;                      // [16 owners][128 p][16 v]
    const int owner = mw * 4 + lk;
#pragma unroll
    for (int nf = 0; nf < 4; ++nf) {
        const int pl = nw * 64 + nf * 16 + lr;
        float* dst = redF + (((long)owner * 128 + pl) << 4);
#pragma unroll
        for (int j = 0; j < 8; ++j) { dst[j] = p1[j][nf]; dst[8 + j] = p2[j][nf]; }
    }
    __syncthreads();
#pragma unroll
    for (int k = 0; k < 4; ++k) {                   // 2048 (p,v) cells / 512 thr
        int v4 = tid * 4 + k;
        int p = v4 >> 4, v = v4 & 15;
        float s = 0.f;
#pragma unroll
        for (int o = 0; o < 16; ++o)
            s += redF[((o * 128 + p) << 4) + v];
        redF[(p << 4) + v] = s;                     // into owner-0 region
    }
    __syncthreads();
    float* lwF = redF + 2048;
    if (tid < 128) {
        float v[16];
#pragma unroll
        for (int k = 0; k < 16; ++k) v[k] = redF[(tid << 4) + k];
        float z0 = b_wl[0], z1 = b_wl[1];
#pragma unroll
        for (int j = 0; j < 8; ++j) {
            float g = bn_l1[j], b = bn_l1[8 + j], m = bn_l1[16 + j], va = bn_l1[24 + j];
            float y = (v[j] - m) * (g * rsqrtf(va + EPS)) + b;
            float sv = y / (1.f + expf(-y));
            z0 += w_wl[j] * sv;
            z1 += w_wl[16 + j] * sv;
            g = bn_l2[j]; b = bn_l2[8 + j]; m = bn_l2[16 + j]; va = bn_l2[24 + j];
            y = (v[8 + j] - m) * (g * rsqrtf(va + EPS)) + b;
            sv = y / (1.f + expf(-y));
            z0 += w_wl[8 + j] * sv;
            z1 += w_wl[24 + j] * sv;
        }
        lwF[tid] = 1.f / (1.f + expf(z1 - z0));
    }
    __syncthreads();

    // ---- phase 3: blend + bf16 rows in LDS + coalesced store ----
    u16* rows = lds + 8192;                         // [128 p][264 co pad] bf16, 67.6 KB
    float lwv[4];
#pragma unroll
    for (int nf = 0; nf < 4; ++nf)
        lwv[nf] = lwF[nw * 64 + nf * 16 + lr];
#pragma unroll
    for (int mf = 0; mf < 4; ++mf) {
        const int co0 = mw * 64 + mf * 16 + lk * 4;
#pragma unroll
        for (int nf = 0; nf < 4; ++nf) {
            const int pl = nw * 64 + nf * 16 + lr;
            const float l0 = lwv[nf], l1 = 1.f - l0;
            unsigned o01, o23;
            {
                float iv0 = in1p[(long)co0 * 4096 + pl];
                float iv1 = in1p[(long)(co0 + 1) * 4096 + pl];
                float iv2 = in1p[(long)(co0 + 2) * 4096 + pl];
                float iv3 = in1p[(long)(co0 + 3) * 4096 + pl];
                u16 a0 = f2bf(iv0 * l0 + (acc[mf][nf][0] + bup[mf][0]) * l1);
                u16 a1 = f2bf(iv1 * l0 + (acc[mf][nf][1] + bup[mf][1]) * l1);
                u16 a2 = f2bf(iv2 * l0 + (acc[mf][nf][2] + bup[mf][2]) * l1);
                u16 a3 = f2bf(iv3 * l0 + (acc[mf][nf][3] + bup[mf][3]) * l1);
                o01 = (unsigned)a0 | ((unsigned)a1 << 16);
                o23 = (unsigned)a2 | ((unsigned)a3 << 16);
            }
            uint2 w2; w2.x = o01; w2.y = o23;
            *(uint2*)(rows + (long)pl * 264 + co0) = w2;
        }
    }
    __syncthreads();
    {
        const int r = tid >> 2, q = tid & 3;
        const int pg = colBase + r;
        const long prow = (long)((pg >> 6) + 1) * 66 + (pg & 63) + 1;
        const uint4* src = (const uint4*)(rows + (long)r * 264 + q * 64);
        uint4* dst = (uint4*)(fusedT + (long)n * 4356 * 256 + prow * 256 + q * 64);
#pragma unroll
        for (int i = 0; i < 8; ++i) dst[i] = src[i];
    }
}

// ---------------- K7: stage-once 9-tap MFMA conv ----------------
template<int KC, int NT, bool PADDED>
__global__ __launch_bounds__(512, 2) void mfma_stage_once_kernel(
    const u16* __restrict__ A,      // [NT][256][KC] bf16
    const u16* __restrict__ B,      // per image [rows][KC] bf16
    const float* __restrict__ scale, const float* __restrict__ shift,
    float* __restrict__ C, long strideB, long strideC, int silu)
{
    constexpr int RROWS = PADDED ? 264 : 128;
    constexpr int ROWU  = KC / 8;
    constexpr int TOT16 = RROWS * ROWU;
    constexpr int NK    = KC / 32;
    constexpr int LOGNK = (NK == 8) ? 3 : 4;
    constexpr int S     = NT * NK;
    __shared__ __align__(16) u16 lds[RROWS * KC];
    const int n = blockIdx.z;
    const u16* Bn = B + (long)n * strideB;
    float* Cn = C + (long)n * strideC;
    const int tid = threadIdx.x;
    const int lane = tid & 63;
    const int wid = tid >> 6;
    const int mw = wid >> 1, nw = wid & 1;          // 4M x 2N
    const int lr = lane & 15, lk = lane >> 4;
    const int colBase = blockIdx.x * 128;
    const int g0 = PADDED ? (colBase >> 6) * 66 : colBase;

    long aBase[4];
#pragma unroll
    for (int mf = 0; mf < 4; ++mf)
        aBase[mf] = (long)(mw * 64 + mf * 16 + lr) * KC + lk * 8;

    for (int f = tid; f < TOT16; f += 512) {
        int r = f >> (LOGNK + 2);
        int u = f & (ROWU - 1);
        const u16* gsrc = Bn + (long)(g0 + r) * KC + ((u ^ (r & 7)) << 3);
        __builtin_amdgcn_global_load_lds(
            (const __attribute__((address_space(1))) void*)gsrc,
            (__attribute__((address_space(3))) void*)(lds + f * 8), 16, 0, 0);
    }

    f32x4 acc[4][4] = {};
    bf16x8 af[2][4], bfr[2][4];
#pragma unroll
    for (int mf = 0; mf < 4; ++mf)
        af[0][mf] = *(const bf16x8*)(A + aBase[mf]);
    __syncthreads();
    {
        int rbase = PADDED ? nw * 66 + lr : nw * 64 + lr;
        const int swz = rbase & 7;
#pragma unroll
        for (int nf = 0; nf < 4; ++nf)
            bfr[0][nf] = *(const bf16x8*)(lds + (rbase + nf * 16) * KC + ((lk ^ swz) << 3));
    }

#pragma unroll 4
    for (int s = 0; s < S; ++s) {
        const int cur = s & 1;
        if (s + 1 < S) {
            const int s1 = s + 1;
            const int t1 = s1 >> LOGNK;
            const int k1 = s1 & (NK - 1);
            const u16* At = A + (long)t1 * 256 * KC + (k1 << 5);
#pragma unroll
            for (int mf = 0; mf < 4; ++mf)
                af[cur ^ 1][mf] = *(const bf16x8*)(At + aBase[mf]);
            int rbase;
            if (PADDED) {
                int dh = t1 / 3 - 1, dw = t1 - (t1 / 3) * 3 - 1;
                rbase = (nw + dh + 1) * 66 + dw + 1 + lr;
            } else {
                rbase = nw * 64 + lr;
            }
            const int swz = rbase & 7;
            const int ub = k1 << 2;
#pragma unroll
            for (int nf = 0; nf < 4; ++nf)
                bfr[cur ^ 1][nf] = *(const bf16x8*)(lds + (rbase + nf * 16) * KC +
                                                    (((ub + lk) ^ swz) << 3));
        }
#pragma unroll
        for (int mf = 0; mf < 4; ++mf)
#pragma unroll
            for (int nf = 0; nf < 4; ++nf)
                acc[mf][nf] = __builtin_amdgcn_mfma_f32_16x16x32_bf16(
                    af[cur][mf], bfr[cur][nf], acc[mf][nf], 0, 0, 0);
    }

#pragma unroll
    for (int mf = 0; mf < 4; ++mf) {
#pragma unroll
        for (int reg = 0; reg < 4; ++reg) {
            int co = mw * 64 + mf * 16 + lk * 4 + reg;
            float sc = scale[co], sh = shift[co];
#pragma unroll
            for (int nf = 0; nf < 4; ++nf) {
                int col = colBase + nw * 64 + nf * 16 + lr;
                float y = acc[mf][nf][reg] * sc + sh;
                if (silu) y = y / (1.f + expf(-y));
                Cn[(long)co * 4096 + col] = y;
            }
        }
    }
}

// ---------------- prep kernels ----------------
__global__ __launch_bounds__(256) void prep_w_kernel(
    const float* __restrict__ w_conv, const float* __restrict__ w_up,
    const float* __restrict__ w_enc,
    u16* __restrict__ wT, u16* __restrict__ wupT, u16* __restrict__ wencT)
{
    int gid = blockIdx.x * 256 + threadIdx.x;
    if (gid < 589824) {             // wT[t][co][ci] = w_conv[co][ci][t]
        int t = gid >> 16;
        int co = (gid >> 8) & 255;
        int ci = gid & 255;
        wT[gid] = f2bf(w_conv[(co * 256 + ci) * 9 + t]);
    }
    if (gid < 131072) wupT[gid] = f2bf(w_up[gid]);
    if (gid < 73728) {              // wencT[t][co<64][ci] (zeros co>=36)
        int t = gid >> 13;
        int co = (gid >> 7) & 63;
        int ci = gid & 127;
        wencT[gid] = (co < 36) ? f2bf(w_enc[(co * 128 + ci) * 9 + t]) : (u16)0;
    }
}

__global__ void prep_bn_kernel(const float* __restrict__ bn_conv,
                               const float* __restrict__ b_up,
                               const float* __restrict__ w_l1,
                               const float* __restrict__ w_l2,
                               float* __restrict__ bnp, float* __restrict__ wlT)
{
    int i = threadIdx.x;            // 256
    float g = bn_conv[i], b = bn_conv[256 + i], m = bn_conv[512 + i], v = bn_conv[768 + i];
    float sc = g * rsqrtf(v + EPS);
    bnp[i] = sc;
    bnp[256 + i] = b - m * sc;
    bnp[512 + i] = 1.f;
    bnp[768 + i] = b_up[i];
#pragma unroll
    for (int j = 0; j < 8; ++j) {
        wlT[i * 16 + j] = w_l1[j * 256 + i];
        wlT[i * 16 + 8 + j] = w_l2[j * 256 + i];
    }
}

extern "C" void kernel_launch(void* const* d_in, const int* in_sizes, int n_in,
                              void* d_out, int out_size, void* d_ws, size_t ws_size,
                              hipStream_t stream)
{
    const float* input1 = (const float*)d_in[0];
    const float* input2 = (const float*)d_in[1];
    const float* w_down = (const float*)d_in[2];
    const float* b_down = (const float*)d_in[3];
    const float* w_enc  = (const float*)d_in[4];
    const float* b_enc  = (const float*)d_in[5];
    const float* w_up   = (const float*)d_in[6];
    const float* b_up   = (const float*)d_in[7];
    const float* w_l1   = (const float*)d_in[8];
    const float* bn_l1  = (const float*)d_in[9];
    const float* w_l2   = (const float*)d_in[10];
    const float* bn_l2  = (const float*)d_in[11];
    const float* w_wl   = (const float*)d_in[12];
    const float* b_wl   = (const float*)d_in[13];
    const float* w_conv = (const float*)d_in[14];
    const float* bn_conv= (const float*)d_in[15];
    float* out = (float*)d_out;

    // workspace layout (float units). ~91 MB total.
    float* ws     = (float*)d_ws;
    float* ktTf   = ws;                      //   591,872 f : ktT bf16 [n][1156][128]
    float* wencTf = ktTf + 591872;           //    36,864 f
    float* kt2    = wencTf + 36864;          //   294,912 f
    float* maskb  = kt2 + 294912;            //   294,912 f
    float* hireb  = maskb + 294912;          // 8,388,608 f : hires bf16 [ci][p]
    float* btb    = hireb + 8388608;         // 8,388,608 f : hiresT bf16 [p][512]
    float* ftbf   = btb + 8388608;           // 4,460,544 f : fusedT bf16 [4356][256]
    float* wTf    = ftbf + 4460544;          //   294,912 f
    float* wupTf  = wTf + 294912;            //    65,536 f
    float* bnp    = wupTf + 65536;           //     1,024 f
    float* wlT    = bnp + 1024;              //     4,096 f
    u16* ktT      = (u16*)ktTf;
    u16* wencT    = (u16*)wencTf;
    u16* hires_bf = (u16*)hireb;
    u16* bt       = (u16*)btb;
    u16* ftb      = (u16*)ftbf;
    u16* wT       = (u16*)wTf;
    u16* wupT     = (u16*)wupTf;

    // prep (independent of data pipeline)
    prep_w_kernel<<<dim3(2304), 256, 0, stream>>>(w_conv, w_up, w_enc, wT, wupT, wencT);
    prep_bn_kernel<<<dim3(1), 256, 0, stream>>>(bn_conv, b_up, w_l1, w_l2, bnp, wlT);
    border_zero_kernel<<<dim3(260), 256, 0, stream>>>(ftb);

    // K1: ktT = bf16T(w_down @ input2 + b_down), padded 34x34 grid
    hipMemsetAsync(ktT, 0, 8L * 1156 * 128 * 2, stream);
    down_gemm_kernel<<<dim3(16, 2, 8), 256, 0, stream>>>(w_down, input2, b_down, ktT);
    // K2: kt2 = 9-tap shifted MFMA GEMM
    enc_mfma_kernel<<<dim3(64, 8), 64, 0, stream>>>(wencT, ktT, b_enc, kt2);
    // K3
    mask_softmax_kernel<<<dim3(128), 256, 0, stream>>>(kt2, maskb);
    // K4: CARAFE -> hires bf16 [ci][p]
    carafe_kernel<<<dim3(16384), 256, 0, stream>>>(input2, maskb, hires_bf);
    // K4b: transpose -> hiresT bf16 [p][512]
    transpose_kernel<<<dim3(128, 8), 256, 0, stream>>>(hires_bf, bt);
    // K5': up-conv + level-attention fuse -> fusedT (u never hits memory)
    up_fuse_kernel<<<dim3(32, 1, 8), 512, 0, stream>>>(
        wupT, bt, input1, bnp, wlT, bn_l1, bn_l2, w_wl, b_wl, ftb);
    // K7: final conv (stage-once 9-tap MFMA) + BN + SiLU
    mfma_stage_once_kernel<256, 9, true><<<dim3(32, 1, 8), 512, 0, stream>>>(
        wT, ftb, bnp, bnp + 256, out, 4356L * 256, 256L * 4096, 1);
}

// Round 10
// 225.678 us; speedup vs baseline: 1.1405x; 1.1207x over previous
//
#include <hip/hip_runtime.h>
#include <math.h>

// ASFF_2: N=8, C1=256, C2=512, H=64, W=64, low-res 32x32.
//  K1 down_gemm: ktT = bf16T(w_down @ input2 + b_down)  [N,34*34,128] padded
//  K2 enc_mfma: kt2 = 9-tap shifted MFMA GEMM           [N,36,1024] fp32
//  K3 softmax -> mask [N,1024,36]
//  K4 CARAFE apply -> hires bf16 [ci][p]                [N,512,4096]
//  K4b transpose -> hiresT bf16 [p][ci]
//  K5 m97-style GEMM (A+B in LDS, dbuf): u = w_up @ hiresT  [N,256,4096] fp32
//  K6 fuse_weights -> lw0 ; border_zero ; transpose_blend -> fusedT bf16
//  K7 m97-style 9-tap conv GEMM + BN + SiLU -> out
// m97 recipe: BOTH operands LDS-staged, 128x128 tile, BK=32, 512-block grid
// (2 blocks/CU co-residency) — inner loop is pure ds_read+MFMA.

#define EPS 1e-5f
typedef unsigned short u16;
typedef __attribute__((ext_vector_type(8))) __bf16 bf16x8;
typedef __attribute__((ext_vector_type(4))) float f32x4;

__device__ inline u16 f2bf(float x) {
    union { float f; unsigned u; } v; v.f = x;
    unsigned r = v.u + 0x7FFF + ((v.u >> 16) & 1);
    return (u16)(r >> 16);
}

// ---------------- K1: fp32 tiled GEMM, bf16-transposed-padded output ----------------
__global__ __launch_bounds__(256) void down_gemm_kernel(
    const float* __restrict__ A, const float* __restrict__ B,
    const float* __restrict__ bias, u16* __restrict__ ktT)
{
    const int n = blockIdx.z;
    const float* Bn = B + (long)n * 512 * 1024;
    __shared__ __align__(16) float As[16][68];
    __shared__ __align__(16) float Bs[16][64];
    const int tid = threadIdx.x;
    const int tcol = tid & 15;
    const int trow = tid >> 4;
    const int rowBase = blockIdx.y * 64;
    const int colBase = blockIdx.x * 64;
    float acc[4][4] = {};
    for (int k0 = 0; k0 < 512; k0 += 16) {
#pragma unroll
        for (int i = 0; i < 4; ++i) {
            int idx = i * 256 + tid;
            int r = idx >> 4, cc = idx & 15;
            As[cc][r] = A[(long)(rowBase + r) * 512 + k0 + cc];
        }
#pragma unroll
        for (int i = 0; i < 4; ++i) {
            int idx = i * 256 + tid;
            int r = idx >> 6, cc = idx & 63;
            Bs[r][cc] = Bn[(long)(k0 + r) * 1024 + colBase + cc];
        }
        __syncthreads();
#pragma unroll
        for (int kk = 0; kk < 16; ++kk) {
            float4 a4 = *reinterpret_cast<const float4*>(&As[kk][trow * 4]);
            float4 b4 = *reinterpret_cast<const float4*>(&Bs[kk][tcol * 4]);
            float a[4] = {a4.x, a4.y, a4.z, a4.w};
            float b[4] = {b4.x, b4.y, b4.z, b4.w};
#pragma unroll
            for (int i = 0; i < 4; ++i)
#pragma unroll
                for (int j = 0; j < 4; ++j)
                    acc[i][j] += a[i] * b[j];
        }
        __syncthreads();
    }
    u16* Kn = ktT + (long)n * 1156 * 128;
#pragma unroll
    for (int i = 0; i < 4; ++i) {
        int ch = rowBase + trow * 4 + i;
        float bv = bias[ch];
#pragma unroll
        for (int j = 0; j < 4; ++j) {
            int p = colBase + tcol * 4 + j;
            int pr = ((p >> 5) + 1) * 34 + (p & 31) + 1;
            Kn[pr * 128 + ch] = f2bf(acc[i][j] + bv);
        }
    }
}

// ---------------- K2: encoder conv as 9-tap shifted MFMA GEMM ----------------
__global__ __launch_bounds__(64) void enc_mfma_kernel(
    const u16* __restrict__ A, const u16* __restrict__ B,
    const float* __restrict__ bias, float* __restrict__ C)
{
    const int n = blockIdx.y;
    const int lane = threadIdx.x;
    const int lr = lane & 15, lk = lane >> 4;
    const int p = blockIdx.x * 16 + lr;
    const int pr = ((p >> 5) + 1) * 34 + (p & 31) + 1;
    const u16* Bn = B + (long)n * 1156 * 128;
    const int bOff = pr * 128 + lk * 8;
    f32x4 acc[3] = {};
    for (int t = 0; t < 9; ++t) {
        const u16* At = A + t * 8192;
        const int btap = ((t / 3 - 1) * 34 + (t % 3 - 1)) * 128;
#pragma unroll
        for (int k0 = 0; k0 < 128; k0 += 32) {
            bf16x8 bf = *(const bf16x8*)(Bn + bOff + btap + k0);
#pragma unroll
            for (int mf = 0; mf < 3; ++mf) {
                bf16x8 af = *(const bf16x8*)(At + (mf * 16 + lr) * 128 + lk * 8 + k0);
                acc[mf] = __builtin_amdgcn_mfma_f32_16x16x32_bf16(af, bf, acc[mf], 0, 0, 0);
            }
        }
    }
    float* Cn = C + (long)n * 36 * 1024;
#pragma unroll
    for (int mf = 0; mf < 3; ++mf)
#pragma unroll
        for (int reg = 0; reg < 4; ++reg) {
            int co = mf * 16 + lk * 4 + reg;
            if (co < 36)
                Cn[(long)co * 1024 + p] = acc[mf][reg] + bias[co];
        }
}

// ---------------- K3: softmax over k=9 ----------------
__global__ __launch_bounds__(256) void mask_softmax_kernel(
    const float* __restrict__ kt2, float* __restrict__ mask)
{
    int gid = blockIdx.x * 256 + threadIdx.x;   // N*1024*4
    int q = gid & 3;
    int p = (gid >> 2) & 1023;
    int n = gid >> 12;
    float s[9];
    float mx = -1e30f;
#pragma unroll
    for (int k = 0; k < 9; ++k) {
        s[k] = kt2[(long)(n * 36 + k * 4 + q) * 1024 + p];
        mx = fmaxf(mx, s[k]);
    }
    float sum = 0.f;
#pragma unroll
    for (int k = 0; k < 9; ++k) { s[k] = expf(s[k] - mx); sum += s[k]; }
    float inv = 1.f / sum;
    float* mp = mask + (long)(n * 1024 + p) * 36 + q;
#pragma unroll
    for (int k = 0; k < 9; ++k) mp[k * 4] = s[k] * inv;
}

// ---------------- K4: CARAFE apply -> hires bf16 [ci][p] ----------------
__global__ __launch_bounds__(256) void carafe_kernel(
    const float* __restrict__ in2, const float* __restrict__ mask,
    u16* __restrict__ hires)
{
    int bx = blockIdx.x;            // N*32*64 : (n, h, cgroup)
    int cg = bx & 63;
    int h = (bx >> 6) & 31;
    int n = bx >> 11;
    int tid = threadIdx.x;
    int w = tid & 31;
    int cl = tid >> 5;
    int c = cg * 8 + cl;
    __shared__ float mrow[32 * 37];
    const float* mg = mask + (long)(n * 1024 + h * 32) * 36;
    for (int idx = tid; idx < 32 * 36; idx += 256) {
        int pw = idx / 36, j = idx - pw * 36;
        mrow[pw * 37 + j] = mg[idx];
    }
    __syncthreads();
    const float* ip = in2 + (long)(n * 512 + c) * 1024;
    float acc[4] = {0.f, 0.f, 0.f, 0.f};
#pragma unroll
    for (int k = 0; k < 9; ++k) {
        int dh = k / 3 - 1, dw = k % 3 - 1;
        int hh = h + dh, ww = w + dw;
        float val = (hh >= 0 && hh < 32 && ww >= 0 && ww < 32) ? ip[hh * 32 + ww] : 0.f;
#pragma unroll
        for (int q = 0; q < 4; ++q)
            acc[q] += val * mrow[w * 37 + k * 4 + q];
    }
    u16* op = hires + (long)(n * 512 + c) * 4096;
#pragma unroll
    for (int q = 0; q < 4; ++q) {
        int r1 = q >> 1, r2 = q & 1;
        op[(2 * h + r1) * 64 + 2 * w + r2] = f2bf(acc[q]);
    }
}

// ---------------- K4b: transpose hires [512][4096] -> hiresT [p][512] ----------------
__global__ __launch_bounds__(256) void transpose_kernel(
    const u16* __restrict__ src0, u16* __restrict__ dst)
{
    constexpr int C = 512, CP = 514;
    __shared__ u16 lds[32 * CP];
    const int n = blockIdx.y;
    const int p0 = blockIdx.x * 32;
    const int tid = threadIdx.x;
    {
        const int w = tid & 31;
        const int chunk = tid >> 5;
        const u16* src = src0 + (long)n * C * 4096 + p0 + w;
        for (int ci = chunk * 64; ci < chunk * 64 + 64; ++ci)
            lds[w * CP + ci] = src[(long)ci * 4096];
    }
    __syncthreads();
    const int px = tid >> 3;
    const int q = tid & 7;
    u16* drow = dst + (long)n * 4096 * C + (long)(p0 + px) * C;
    const u16* lrow = lds + px * CP;
#pragma unroll
    for (int j = 0; j < C / 16; ++j) {
        int off = j * 16 + q * 2;
        *(unsigned*)(drow + off) = *(const unsigned*)(lrow + off);
    }
}

// ---------------- border_zero: zero the 66x66 pad ring of fusedT ----------------
__global__ __launch_bounds__(256) void border_zero_kernel(u16* __restrict__ ftb)
{
    int gid = blockIdx.x * 256 + threadIdx.x;   // 8 * 260 * 32 uint4
    if (gid >= 8 * 260 * 32) return;
    int n = gid / (260 * 32);
    int rem = gid - n * (260 * 32);
    int r = rem >> 5;
    int i = rem & 31;
    int h, w;
    if (r < 66)       { h = 0;  w = r; }
    else if (r < 132) { h = 65; w = r - 66; }
    else { int j = r - 132; h = 1 + (j >> 1); w = (j & 1) * 65; }
    long prow = (long)h * 66 + w;
    uint4* dst = (uint4*)(ftb + (long)n * 4356 * 256 + prow * 256) + i;
    *dst = make_uint4(0, 0, 0, 0);
}

// ---------------- K6b: fused blend + transpose-cast to padded fusedT ----------------
__global__ __launch_bounds__(256) void transpose_blend_kernel(
    const float* __restrict__ i1g, const float* __restrict__ ug,
    const float* __restrict__ lw0g, u16* __restrict__ dst)
{
    constexpr int C = 256, CP = 258;
    __shared__ u16 lds[32 * CP];
    const int n = blockIdx.y;
    const int p0 = blockIdx.x * 32;
    const int tid = threadIdx.x;
    {
        const int w = tid & 31;
        const int chunk = tid >> 5;
        const int p = p0 + w;
        const float lw = lw0g[n * 4096 + p];
        const float lw1 = 1.f - lw;
        const float* s1 = i1g + (long)n * C * 4096 + p;
        const float* s2 = ug + (long)n * C * 4096 + p;
        for (int ci = chunk * 32; ci < chunk * 32 + 32; ++ci)
            lds[w * CP + ci] = f2bf(s1[(long)ci * 4096] * lw + s2[(long)ci * 4096] * lw1);
    }
    __syncthreads();
    const int px = tid >> 3;
    const int q = tid & 7;
    const int p = p0 + px;
    long prow = (long)((p >> 6) + 1) * 66 + (p & 63) + 1;
    u16* drow = dst + (long)n * 4356 * C + prow * C;
    const u16* lrow = lds + px * CP;
#pragma unroll
    for (int j = 0; j < C / 16; ++j) {
        int off = j * 16 + q * 2;
        *(unsigned*)(drow + off) = *(const unsigned*)(lrow + off);
    }
}

// ---------------- K5/K7: m97-style GEMM — BOTH operands LDS-staged ----------------
// 128x128 tile, BK=32, 256 thr = 4 waves (2M x 2N), grid (32, 2, 8) = 512 blocks
// = 2 blocks/CU. Per phase (kx,t): barrier -> issue next A-stage (8 KB) [and next
// B-stage 16.9 KB at t==0] -> ds_read frags -> 16 MFMA. Inner loop has NO global
// loads; vmem queue holds only staging (drained by the barrier, m97 pattern).
#define STAGE_A(buf, t, kx)                                                          \
    {                                                                                \
        const u16* Abase = A + ((long)(t) * 256 + rowBase) * KCC + (kx) * 32;        \
        for (int f = tid; f < 512; f += 256) {                                       \
            int r = f >> 2, u = f & 3;                                               \
            __builtin_amdgcn_global_load_lds(                                        \
                (const __attribute__((address_space(1))) void*)                      \
                    (Abase + (long)r * KCC + ((u ^ (r & 3)) << 3)),                  \
                (__attribute__((address_space(3))) void*)(&lsA[buf][f * 8]),         \
                16, 0, 0);                                                           \
        }                                                                            \
    }

#define STAGE_B(buf, kx)                                                             \
    {                                                                                \
        const u16* Bbase = Bn + (long)g0 * KCC + (kx) * 32;                          \
        for (int f = tid; f < BUNITS; f += 256) {                                    \
            int r = f >> 2, u = f & 3;                                               \
            __builtin_amdgcn_global_load_lds(                                        \
                (const __attribute__((address_space(1))) void*)                      \
                    (Bbase + (long)r * KCC + ((u ^ (r & 3)) << 3)),                  \
                (__attribute__((address_space(3))) void*)(&lsB[buf][f * 8]),         \
                16, 0, 0);                                                           \
        }                                                                            \
    }

template<int KCC, int NT, bool PADDED>
__global__ __launch_bounds__(256, 2) void gemm_m97_kernel(
    const u16* __restrict__ A,      // [NT][256][KCC] bf16
    const u16* __restrict__ B,      // per image [rows][KCC] bf16
    const float* __restrict__ scale, const float* __restrict__ shift,
    float* __restrict__ C, long strideB, long strideC, int silu)
{
    constexpr int RROWS = PADDED ? 264 : 128;
    constexpr int BUNITS = RROWS * 4;       // 16B units per B buffer
    constexpr int NKX = KCC / 32;
    constexpr int S = NKX * NT;
    __shared__ __align__(16) u16 lsA[2][128 * 32];
    __shared__ __align__(16) u16 lsB[2][RROWS * 32];
    const int n = blockIdx.z;
    const u16* Bn = B + (long)n * strideB;
    float* Cn = C + (long)n * strideC;
    const int tid = threadIdx.x;
    const int lane = tid & 63;
    const int wid = tid >> 6;
    const int mw = wid >> 1, nw = wid & 1;  // 2M x 2N, wave tile 64x64
    const int lr = lane & 15, lk = lane >> 4;
    const int rowBase = blockIdx.y * 128;
    const int colBase = blockIdx.x * 128;
    const int g0 = PADDED ? (colBase >> 6) * 66 : colBase;

    STAGE_B(0, 0);
    STAGE_A(0, 0, 0);

    const int aswz = (lk ^ (lr & 3)) << 3;  // co&3 == lr&3 (16|64 ≡ 0 mod 4)
    int aoff[4];
#pragma unroll
    for (int mf = 0; mf < 4; ++mf)
        aoff[mf] = (mw * 64 + mf * 16 + lr) * 32 + aswz;

    f32x4 acc[4][4] = {};
    for (int kx = 0; kx < NKX; ++kx) {
#pragma unroll
        for (int t = 0; t < NT; ++t) {
            const int s = kx * NT + t;
            __syncthreads();                 // drains staging for this phase
            if (t == 0 && kx + 1 < NKX) STAGE_B((kx + 1) & 1, kx + 1);
            if (s + 1 < S) {
                const int t1 = (t + 1 == NT) ? 0 : t + 1;
                const int kx1 = (t + 1 == NT) ? kx + 1 : kx;
                STAGE_A((s + 1) & 1, t1, kx1);
            }
            const u16* la = lsA[s & 1];
            const u16* lb = lsB[kx & 1];
            bf16x8 af[4], bfr[4];
#pragma unroll
            for (int mf = 0; mf < 4; ++mf)
                af[mf] = *(const bf16x8*)(la + aoff[mf]);
            int rb;
            if (PADDED) {
                int dh = t / 3 - 1, dw = t - (t / 3) * 3 - 1;
                rb = (nw + dh + 1) * 66 + dw + 1 + lr;
            } else {
                rb = nw * 64 + lr;
            }
            const int bswz = (lk ^ (rb & 3)) << 3;   // (rb+nf*16)&3 == rb&3
#pragma unroll
            for (int nf = 0; nf < 4; ++nf)
                bfr[nf] = *(const bf16x8*)(lb + (rb + nf * 16) * 32 + bswz);
#pragma unroll
            for (int mf = 0; mf < 4; ++mf)
#pragma unroll
                for (int nf = 0; nf < 4; ++nf)
                    acc[mf][nf] = __builtin_amdgcn_mfma_f32_16x16x32_bf16(
                        af[mf], bfr[nf], acc[mf][nf], 0, 0, 0);
        }
    }

#pragma unroll
    for (int mf = 0; mf < 4; ++mf) {
#pragma unroll
        for (int reg = 0; reg < 4; ++reg) {
            int co = rowBase + mw * 64 + mf * 16 + lk * 4 + reg;
            float sc = scale[co], sh = shift[co];
#pragma unroll
            for (int nf = 0; nf < 4; ++nf) {
                int col = colBase + nw * 64 + nf * 16 + lr;
                float y = acc[mf][nf][reg] * sc + sh;
                if (silu) y = y / (1.f + expf(-y));
                Cn[(long)co * 4096 + col] = y;
            }
        }
    }
}

// ---------------- K6: level weights (softmax over 2) -> lw0[n][p] ----------------
__global__ __launch_bounds__(256) void fuse_weights_kernel(
    const float* __restrict__ input1, const float* __restrict__ u,
    const float* __restrict__ w_l1, const float* __restrict__ bn_l1,
    const float* __restrict__ w_l2, const float* __restrict__ bn_l2,
    const float* __restrict__ w_wl, const float* __restrict__ b_wl,
    float* __restrict__ lw0g)
{
    int bx = blockIdx.x;            // 8 * 64
    int n = bx >> 6;
    int p0 = (bx & 63) * 64;
    int tid = threadIdx.x;
    int pos = tid & 63;
    int chunk = tid >> 6;
    int p = p0 + pos;
    const float* i1 = input1 + (long)n * 256 * 4096;
    const float* i2 = u + (long)n * 256 * 4096;
    float s1[8] = {}, s2[8] = {};
    for (int ci = chunk * 64; ci < chunk * 64 + 64; ++ci) {
        float x1 = i1[(long)ci * 4096 + p];
        float x2 = i2[(long)ci * 4096 + p];
#pragma unroll
        for (int j = 0; j < 8; ++j) {
            s1[j] += w_l1[j * 256 + ci] * x1;
            s2[j] += w_l2[j * 256 + ci] * x2;
        }
    }
    __shared__ float red[4][64][16];
#pragma unroll
    for (int j = 0; j < 8; ++j) { red[chunk][pos][j] = s1[j]; red[chunk][pos][8 + j] = s2[j]; }
    __syncthreads();
    if (tid < 64) {
        float v[16];
#pragma unroll
        for (int j = 0; j < 16; ++j)
            v[j] = red[0][tid][j] + red[1][tid][j] + red[2][tid][j] + red[3][tid][j];
        float z0 = b_wl[0], z1 = b_wl[1];
#pragma unroll
        for (int j = 0; j < 8; ++j) {
            float g = bn_l1[j], b = bn_l1[8 + j], m = bn_l1[16 + j], va = bn_l1[24 + j];
            float y = (v[j] - m) * (g * rsqrtf(va + EPS)) + b;
            float sv = y / (1.f + expf(-y));
            z0 += w_wl[j] * sv;
            z1 += w_wl[16 + j] * sv;
            g = bn_l2[j]; b = bn_l2[8 + j]; m = bn_l2[16 + j]; va = bn_l2[24 + j];
            y = (v[8 + j] - m) * (g * rsqrtf(va + EPS)) + b;
            sv = y / (1.f + expf(-y));
            z0 += w_wl[8 + j] * sv;
            z1 += w_wl[24 + j] * sv;
        }
        lw0g[n * 4096 + p0 + tid] = 1.f / (1.f + expf(z1 - z0));
    }
}

// ---------------- prep kernels ----------------
__global__ __launch_bounds__(256) void prep_w_kernel(
    const float* __restrict__ w_conv, const float* __restrict__ w_up,
    const float* __restrict__ w_enc,
    u16* __restrict__ wT, u16* __restrict__ wupT, u16* __restrict__ wencT)
{
    int gid = blockIdx.x * 256 + threadIdx.x;
    if (gid < 589824) {             // wT[t][co][ci] = w_conv[co][ci][t]
        int t = gid >> 16;
        int co = (gid >> 8) & 255;
        int ci = gid & 255;
        wT[gid] = f2bf(w_conv[(co * 256 + ci) * 9 + t]);
    }
    if (gid < 131072) wupT[gid] = f2bf(w_up[gid]);
    if (gid < 73728) {              // wencT[t][co<64][ci] (zeros co>=36)
        int t = gid >> 13;
        int co = (gid >> 7) & 63;
        int ci = gid & 127;
        wencT[gid] = (co < 36) ? f2bf(w_enc[(co * 128 + ci) * 9 + t]) : (u16)0;
    }
}

__global__ void prep_bn_kernel(const float* __restrict__ bn_conv,
                               const float* __restrict__ b_up, float* __restrict__ bnp)
{
    int i = threadIdx.x;            // 256
    float g = bn_conv[i], b = bn_conv[256 + i], m = bn_conv[512 + i], v = bn_conv[768 + i];
    float sc = g * rsqrtf(v + EPS);
    bnp[i] = sc;
    bnp[256 + i] = b - m * sc;
    bnp[512 + i] = 1.f;
    bnp[768 + i] = b_up[i];
}

extern "C" void kernel_launch(void* const* d_in, const int* in_sizes, int n_in,
                              void* d_out, int out_size, void* d_ws, size_t ws_size,
                              hipStream_t stream)
{
    const float* input1 = (const float*)d_in[0];
    const float* input2 = (const float*)d_in[1];
    const float* w_down = (const float*)d_in[2];
    const float* b_down = (const float*)d_in[3];
    const float* w_enc  = (const float*)d_in[4];
    const float* b_enc  = (const float*)d_in[5];
    const float* w_up   = (const float*)d_in[6];
    const float* b_up   = (const float*)d_in[7];
    const float* w_l1   = (const float*)d_in[8];
    const float* bn_l1  = (const float*)d_in[9];
    const float* w_l2   = (const float*)d_in[10];
    const float* bn_l2  = (const float*)d_in[11];
    const float* w_wl   = (const float*)d_in[12];
    const float* b_wl   = (const float*)d_in[13];
    const float* w_conv = (const float*)d_in[14];
    const float* bn_conv= (const float*)d_in[15];
    float* out = (float*)d_out;

    // workspace layout (float units). ~74 MB total (aliased).
    float* ws     = (float*)d_ws;
    float* ktTf   = ws;                      //   591,872 f : ktT bf16 [n][1156][128]
    float* wencTf = ktTf + 591872;           //    36,864 f
    float* kt2    = wencTf + 36864;          //   294,912 f
    float* maskb  = kt2 + 294912;            //   294,912 f
    float* hireb  = maskb + 294912;          // 8,388,608 f : hires bf16 -> later u fp32
    float* btb    = hireb + 8388608;         // 8,388,608 f : hiresT bf16 -> later fusedT bf16
    float* wTf    = btb + 8388608;           //   294,912 f
    float* wupTf  = wTf + 294912;            //    65,536 f
    float* bnp    = wupTf + 65536;           //     1,024 f
    float* lw0g   = bnp + 1024;              //    32,768 f
    u16* ktT      = (u16*)ktTf;
    u16* wencT    = (u16*)wencTf;
    u16* hires_bf = (u16*)hireb;             // dead after transpose
    float* u      = hireb;                   // fp32 u overlays hires after K4b
    u16* bt       = (u16*)btb;               // hiresT; dead after K5
    u16* ftb      = (u16*)btb;               // fusedT overlays hiresT after K5
    u16* wT       = (u16*)wTf;
    u16* wupT     = (u16*)wupTf;

    // prep (independent of data pipeline)
    prep_w_kernel<<<dim3(2304), 256, 0, stream>>>(w_conv, w_up, w_enc, wT, wupT, wencT);
    prep_bn_kernel<<<dim3(1), 256, 0, stream>>>(bn_conv, b_up, bnp);

    // K1: ktT = bf16T(w_down @ input2 + b_down), padded 34x34 grid
    hipMemsetAsync(ktT, 0, 8L * 1156 * 128 * 2, stream);
    down_gemm_kernel<<<dim3(16, 2, 8), 256, 0, stream>>>(w_down, input2, b_down, ktT);
    // K2: kt2 = 9-tap shifted MFMA GEMM
    enc_mfma_kernel<<<dim3(64, 8), 64, 0, stream>>>(wencT, ktT, b_enc, kt2);
    // K3
    mask_softmax_kernel<<<dim3(128), 256, 0, stream>>>(kt2, maskb);
    // K4: CARAFE -> hires bf16 [ci][p]
    carafe_kernel<<<dim3(16384), 256, 0, stream>>>(input2, maskb, hires_bf);
    // K4b: transpose -> hiresT bf16 [p][512]
    transpose_kernel<<<dim3(128, 8), 256, 0, stream>>>(hires_bf, bt);
    // K5: u = w_up @ hiresT + b_up (m97-style, A+B in LDS, 512 blocks)
    gemm_m97_kernel<512, 1, false><<<dim3(32, 2, 8), 256, 0, stream>>>(
        wupT, bt, bnp + 512, bnp + 768, u, 4096L * 512, 256L * 4096, 0);
    // K6: level weights -> lw0
    fuse_weights_kernel<<<dim3(512), 256, 0, stream>>>(
        input1, u, w_l1, bn_l1, w_l2, bn_l2, w_wl, b_wl, lw0g);
    // fusedT overlays hiresT (dead after K5): zero pad ring, blend interior
    border_zero_kernel<<<dim3(260), 256, 0, stream>>>(ftb);
    transpose_blend_kernel<<<dim3(128, 8), 256, 0, stream>>>(input1, u, lw0g, ftb);
    // K7: final conv (m97-style 9-tap) + BN + SiLU
    gemm_m97_kernel<256, 9, true><<<dim3(32, 2, 8), 256, 0, stream>>>(
        wT, ftb, bnp, bnp + 256, out, 4356L * 256, 256L * 4096, 1);
}

// Round 11
// 204.759 us; speedup vs baseline: 1.2571x; 1.1022x over previous
//
#include <hip/hip_runtime.h>
#include <math.h>

// ASFF_2: N=8, C1=256, C2=512, H=64, W=64, low-res 32x32.
//  K1 down_gemm: ktT = bf16T(w_down @ input2 + b_down)  [N,34*34,128] padded
//  K2 enc_mfma: kt2 = 9-tap shifted MFMA GEMM           [N,36,1024] fp32
//  K3 softmax -> mask [N,1024,36]
//  K4 CARAFE apply -> hires bf16 [ci][p]                [N,512,4096]
//  K4b transpose -> hiresT bf16 [p][ci]
//  K5 m97+T4 GEMM (triple-buf LDS, counted vmcnt): u = w_up @ hiresT
//  K6 fuse_blend: lw0 in-block + blend + transpose -> fusedT bf16
//  K7 m97+T4 9-tap conv GEMM + BN + SiLU -> out
// T4: stage issued -> s_waitcnt vmcnt(N) (N = loads issued this phase) ->
// raw s_barrier; triple-buffered LDS removes the WAR that forced vmcnt(0).

#define EPS 1e-5f
typedef unsigned short u16;
typedef __attribute__((ext_vector_type(8))) __bf16 bf16x8;
typedef __attribute__((ext_vector_type(4))) float f32x4;

#define VMCNT(N) asm volatile("s_waitcnt vmcnt(" #N ")" ::: "memory")

__device__ inline u16 f2bf(float x) {
    union { float f; unsigned u; } v; v.f = x;
    unsigned r = v.u + 0x7FFF + ((v.u >> 16) & 1);
    return (u16)(r >> 16);
}

// ---------------- K1: fp32 tiled GEMM, bf16-transposed-padded output ----------------
__global__ __launch_bounds__(256) void down_gemm_kernel(
    const float* __restrict__ A, const float* __restrict__ B,
    const float* __restrict__ bias, u16* __restrict__ ktT)
{
    const int n = blockIdx.z;
    const float* Bn = B + (long)n * 512 * 1024;
    __shared__ __align__(16) float As[16][68];
    __shared__ __align__(16) float Bs[16][64];
    const int tid = threadIdx.x;
    const int tcol = tid & 15;
    const int trow = tid >> 4;
    const int rowBase = blockIdx.y * 64;
    const int colBase = blockIdx.x * 64;
    float acc[4][4] = {};
    for (int k0 = 0; k0 < 512; k0 += 16) {
#pragma unroll
        for (int i = 0; i < 4; ++i) {
            int idx = i * 256 + tid;
            int r = idx >> 4, cc = idx & 15;
            As[cc][r] = A[(long)(rowBase + r) * 512 + k0 + cc];
        }
#pragma unroll
        for (int i = 0; i < 4; ++i) {
            int idx = i * 256 + tid;
            int r = idx >> 6, cc = idx & 63;
            Bs[r][cc] = Bn[(long)(k0 + r) * 1024 + colBase + cc];
        }
        __syncthreads();
#pragma unroll
        for (int kk = 0; kk < 16; ++kk) {
            float4 a4 = *reinterpret_cast<const float4*>(&As[kk][trow * 4]);
            float4 b4 = *reinterpret_cast<const float4*>(&Bs[kk][tcol * 4]);
            float a[4] = {a4.x, a4.y, a4.z, a4.w};
            float b[4] = {b4.x, b4.y, b4.z, b4.w};
#pragma unroll
            for (int i = 0; i < 4; ++i)
#pragma unroll
                for (int j = 0; j < 4; ++j)
                    acc[i][j] += a[i] * b[j];
        }
        __syncthreads();
    }
    u16* Kn = ktT + (long)n * 1156 * 128;
#pragma unroll
    for (int i = 0; i < 4; ++i) {
        int ch = rowBase + trow * 4 + i;
        float bv = bias[ch];
#pragma unroll
        for (int j = 0; j < 4; ++j) {
            int p = colBase + tcol * 4 + j;
            int pr = ((p >> 5) + 1) * 34 + (p & 31) + 1;
            Kn[pr * 128 + ch] = f2bf(acc[i][j] + bv);
        }
    }
}

// ---------------- K2: encoder conv as 9-tap shifted MFMA GEMM ----------------
__global__ __launch_bounds__(64) void enc_mfma_kernel(
    const u16* __restrict__ A, const u16* __restrict__ B,
    const float* __restrict__ bias, float* __restrict__ C)
{
    const int n = blockIdx.y;
    const int lane = threadIdx.x;
    const int lr = lane & 15, lk = lane >> 4;
    const int p = blockIdx.x * 16 + lr;
    const int pr = ((p >> 5) + 1) * 34 + (p & 31) + 1;
    const u16* Bn = B + (long)n * 1156 * 128;
    const int bOff = pr * 128 + lk * 8;
    f32x4 acc[3] = {};
    for (int t = 0; t < 9; ++t) {
        const u16* At = A + t * 8192;
        const int btap = ((t / 3 - 1) * 34 + (t % 3 - 1)) * 128;
#pragma unroll
        for (int k0 = 0; k0 < 128; k0 += 32) {
            bf16x8 bf = *(const bf16x8*)(Bn + bOff + btap + k0);
#pragma unroll
            for (int mf = 0; mf < 3; ++mf) {
                bf16x8 af = *(const bf16x8*)(At + (mf * 16 + lr) * 128 + lk * 8 + k0);
                acc[mf] = __builtin_amdgcn_mfma_f32_16x16x32_bf16(af, bf, acc[mf], 0, 0, 0);
            }
        }
    }
    float* Cn = C + (long)n * 36 * 1024;
#pragma unroll
    for (int mf = 0; mf < 3; ++mf)
#pragma unroll
        for (int reg = 0; reg < 4; ++reg) {
            int co = mf * 16 + lk * 4 + reg;
            if (co < 36)
                Cn[(long)co * 1024 + p] = acc[mf][reg] + bias[co];
        }
}

// ---------------- K3: softmax over k=9 ----------------
__global__ __launch_bounds__(256) void mask_softmax_kernel(
    const float* __restrict__ kt2, float* __restrict__ mask)
{
    int gid = blockIdx.x * 256 + threadIdx.x;   // N*1024*4
    int q = gid & 3;
    int p = (gid >> 2) & 1023;
    int n = gid >> 12;
    float s[9];
    float mx = -1e30f;
#pragma unroll
    for (int k = 0; k < 9; ++k) {
        s[k] = kt2[(long)(n * 36 + k * 4 + q) * 1024 + p];
        mx = fmaxf(mx, s[k]);
    }
    float sum = 0.f;
#pragma unroll
    for (int k = 0; k < 9; ++k) { s[k] = expf(s[k] - mx); sum += s[k]; }
    float inv = 1.f / sum;
    float* mp = mask + (long)(n * 1024 + p) * 36 + q;
#pragma unroll
    for (int k = 0; k < 9; ++k) mp[k * 4] = s[k] * inv;
}

// ---------------- K4: CARAFE apply -> hires bf16 [ci][p] ----------------
__global__ __launch_bounds__(256) void carafe_kernel(
    const float* __restrict__ in2, const float* __restrict__ mask,
    u16* __restrict__ hires)
{
    int bx = blockIdx.x;            // N*32*64 : (n, h, cgroup)
    int cg = bx & 63;
    int h = (bx >> 6) & 31;
    int n = bx >> 11;
    int tid = threadIdx.x;
    int w = tid & 31;
    int cl = tid >> 5;
    int c = cg * 8 + cl;
    __shared__ float mrow[32 * 37];
    const float* mg = mask + (long)(n * 1024 + h * 32) * 36;
    for (int idx = tid; idx < 32 * 36; idx += 256) {
        int pw = idx / 36, j = idx - pw * 36;
        mrow[pw * 37 + j] = mg[idx];
    }
    __syncthreads();
    const float* ip = in2 + (long)(n * 512 + c) * 1024;
    float acc[4] = {0.f, 0.f, 0.f, 0.f};
#pragma unroll
    for (int k = 0; k < 9; ++k) {
        int dh = k / 3 - 1, dw = k % 3 - 1;
        int hh = h + dh, ww = w + dw;
        float val = (hh >= 0 && hh < 32 && ww >= 0 && ww < 32) ? ip[hh * 32 + ww] : 0.f;
#pragma unroll
        for (int q = 0; q < 4; ++q)
            acc[q] += val * mrow[w * 37 + k * 4 + q];
    }
    u16* op = hires + (long)(n * 512 + c) * 4096;
#pragma unroll
    for (int q = 0; q < 4; ++q) {
        int r1 = q >> 1, r2 = q & 1;
        op[(2 * h + r1) * 64 + 2 * w + r2] = f2bf(acc[q]);
    }
}

// ---------------- K4b: transpose hires [512][4096] -> hiresT [p][512] ----------------
__global__ __launch_bounds__(256) void transpose_kernel(
    const u16* __restrict__ src0, u16* __restrict__ dst)
{
    constexpr int C = 512, CP = 514;
    __shared__ u16 lds[32 * CP];
    const int n = blockIdx.y;
    const int p0 = blockIdx.x * 32;
    const int tid = threadIdx.x;
    {
        const int w = tid & 31;
        const int chunk = tid >> 5;
        const u16* src = src0 + (long)n * C * 4096 + p0 + w;
        for (int ci = chunk * 64; ci < chunk * 64 + 64; ++ci)
            lds[w * CP + ci] = src[(long)ci * 4096];
    }
    __syncthreads();
    const int px = tid >> 3;
    const int q = tid & 7;
    u16* drow = dst + (long)n * 4096 * C + (long)(p0 + px) * C;
    const u16* lrow = lds + px * CP;
#pragma unroll
    for (int j = 0; j < C / 16; ++j) {
        int off = j * 16 + q * 2;
        *(unsigned*)(drow + off) = *(const unsigned*)(lrow + off);
    }
}

// ---------------- border_zero: zero the 66x66 pad ring of fusedT ----------------
__global__ __launch_bounds__(256) void border_zero_kernel(u16* __restrict__ ftb)
{
    int gid = blockIdx.x * 256 + threadIdx.x;   // 8 * 260 * 32 uint4
    if (gid >= 8 * 260 * 32) return;
    int n = gid / (260 * 32);
    int rem = gid - n * (260 * 32);
    int r = rem >> 5;
    int i = rem & 31;
    int h, w;
    if (r < 66)       { h = 0;  w = r; }
    else if (r < 132) { h = 65; w = r - 66; }
    else { int j = r - 132; h = 1 + (j >> 1); w = (j & 1) * 65; }
    long prow = (long)h * 66 + w;
    uint4* dst = (uint4*)(ftb + (long)n * 4356 * 256 + prow * 256) + i;
    *dst = make_uint4(0, 0, 0, 0);
}

// ---------------- K6: merged level-attention weights + blend + transpose ----------------
// Per block: 32 pixels. Pass1: s1/s2 partials over 256 ch -> LDS reduce -> lw0.
// Pass2: re-read i1/u (L2-hot), blend, bf16, transposed padded write.
__global__ __launch_bounds__(256) void fuse_blend_kernel(
    const float* __restrict__ i1g, const float* __restrict__ ug,
    const float* __restrict__ w_l1, const float* __restrict__ bn_l1,
    const float* __restrict__ w_l2, const float* __restrict__ bn_l2,
    const float* __restrict__ w_wl, const float* __restrict__ b_wl,
    u16* __restrict__ dst)
{
    __shared__ float red[8][32][16];            // 16 KB
    __shared__ float lw0s[32];
    __shared__ u16 lds2[32 * 258];              // 16.5 KB
    const int n = blockIdx.y;
    const int p0 = blockIdx.x * 32;
    const int tid = threadIdx.x;
    const int w = tid & 31;
    const int chunk = tid >> 5;                 // 0..7, 32 ch each
    const int p = p0 + w;
    const float* i1 = i1g + (long)n * 256 * 4096 + p;
    const float* uu = ug + (long)n * 256 * 4096 + p;
    {
        float s1[8] = {}, s2[8] = {};
        for (int ci = chunk * 32; ci < chunk * 32 + 32; ++ci) {
            float x1 = i1[(long)ci * 4096];
            float x2 = uu[(long)ci * 4096];
#pragma unroll
            for (int j = 0; j < 8; ++j) {
                s1[j] += w_l1[j * 256 + ci] * x1;
                s2[j] += w_l2[j * 256 + ci] * x2;
            }
        }
#pragma unroll
        for (int j = 0; j < 8; ++j) { red[chunk][w][j] = s1[j]; red[chunk][w][8 + j] = s2[j]; }
    }
    __syncthreads();
#pragma unroll
    for (int k = 0; k < 2; ++k) {               // 512 cells / 256 thr
        int cell = tid * 2 + k;
        int px = cell >> 4, v = cell & 15;
        float s = 0.f;
#pragma unroll
        for (int o = 0; o < 8; ++o) s += red[o][px][v];
        red[0][px][v] = s;
    }
    __syncthreads();
    if (tid < 32) {
        float v[16];
#pragma unroll
        for (int k = 0; k < 16; ++k) v[k] = red[0][tid][k];
        float z0 = b_wl[0], z1 = b_wl[1];
#pragma unroll
        for (int j = 0; j < 8; ++j) {
            float g = bn_l1[j], b = bn_l1[8 + j], m = bn_l1[16 + j], va = bn_l1[24 + j];
            float y = (v[j] - m) * (g * rsqrtf(va + EPS)) + b;
            float sv = y / (1.f + expf(-y));
            z0 += w_wl[j] * sv;
            z1 += w_wl[16 + j] * sv;
            g = bn_l2[j]; b = bn_l2[8 + j]; m = bn_l2[16 + j]; va = bn_l2[24 + j];
            y = (v[8 + j] - m) * (g * rsqrtf(va + EPS)) + b;
            sv = y / (1.f + expf(-y));
            z0 += w_wl[8 + j] * sv;
            z1 += w_wl[24 + j] * sv;
        }
        lw0s[tid] = 1.f / (1.f + expf(z1 - z0));
    }
    __syncthreads();
    {
        const float lw = lw0s[w], lw1 = 1.f - lw;
        for (int ci = chunk * 32; ci < chunk * 32 + 32; ++ci)
            lds2[w * 258 + ci] = f2bf(i1[(long)ci * 4096] * lw + uu[(long)ci * 4096] * lw1);
    }
    __syncthreads();
    {
        const int px = tid >> 3;
        const int q = tid & 7;
        const int pg = p0 + px;
        long prow = (long)((pg >> 6) + 1) * 66 + (pg & 63) + 1;
        u16* drow = dst + (long)n * 4356 * 256 + prow * 256;
        const u16* lrow = lds2 + px * 258;
#pragma unroll
        for (int j = 0; j < 16; ++j) {
            int off = j * 16 + q * 2;
            *(unsigned*)(drow + off) = *(const unsigned*)(lrow + off);
        }
    }
}

// ---------------- K5/K7: m97+T4 GEMM — triple-buf LDS, counted vmcnt ----------------
// 128x128 tile, BK=32, 4 waves (2M x 2N), grid (32,2,8) = 512 blocks = 2/CU.
// Phase s: issue stage(s+1) -> vmcnt(issued-this-phase) -> s_barrier -> ds_read
// buf[s%3] -> 16 MFMA. Triple-buffer makes stage(s+1) WAR-safe (max skew 1 phase).
// Swizzle: unit ^ ((row>>1)&3) on stage-source and read (2-way = free, m136).
#define STAGE_A(dstp, t, kx)                                                         \
    {                                                                                \
        const u16* Abase = A + ((long)(t) * 256 + rowBase) * KCC + (kx) * 32;        \
        _Pragma("unroll")                                                            \
        for (int ii = 0; ii < 2; ++ii) {                                             \
            int f = ii * 256 + tid;                                                  \
            int r = f >> 2, uu = f & 3;                                              \
            __builtin_amdgcn_global_load_lds(                                        \
                (const __attribute__((address_space(1))) void*)                      \
                    (Abase + (long)r * KCC + ((uu ^ ((r >> 1) & 3)) << 3)),          \
                (__attribute__((address_space(3))) void*)((dstp) + f * 8),           \
                16, 0, 0);                                                           \
        }                                                                            \
    }

#define STAGE_B(dstp, kx)                                                            \
    {                                                                                \
        const u16* Bbase = Bn + (long)g0 * KCC + (kx) * 32;                          \
        for (int f = tid; f < BUNITS; f += 256) {                                    \
            int r = f >> 2, uu = f & 3;                                              \
            __builtin_amdgcn_global_load_lds(                                        \
                (const __attribute__((address_space(1))) void*)                      \
                    (Bbase + (long)r * KCC + ((uu ^ ((r >> 1) & 3)) << 3)),          \
                (__attribute__((address_space(3))) void*)((dstp) + f * 8),           \
                16, 0, 0);                                                           \
        }                                                                            \
    }

template<int KCC, int NT, bool PADDED>
__global__ __launch_bounds__(256, 2) void gemm_m97_kernel(
    const u16* __restrict__ A,      // [NT][256][KCC] bf16
    const u16* __restrict__ B,      // per image [rows][KCC] bf16
    const float* __restrict__ scale, const float* __restrict__ shift,
    float* __restrict__ C, long strideB, long strideC, int silu)
{
    constexpr int RROWS = PADDED ? 264 : 128;
    constexpr int BUNITS = RROWS * 4;       // 1056 (K7) | 512 (K5)
    constexpr int NKX = KCC / 32;
    constexpr int MINB = BUNITS / 256;      // floor: 4 | 2 (min B loads/thread)
    __shared__ __align__(16) u16 lsA[3][128 * 32];
    __shared__ __align__(16) u16 lsB[3][RROWS * 32];
    const int n = blockIdx.z;
    const u16* Bn = B + (long)n * strideB;
    float* Cn = C + (long)n * strideC;
    const int tid = threadIdx.x;
    const int lane = tid & 63;
    const int wid = tid >> 6;
    const int mw = wid >> 1, nw = wid & 1;  // 2M x 2N, wave tile 64x64
    const int lr = lane & 15, lk = lane >> 4;
    const int rowBase = blockIdx.y * 128;
    const int colBase = blockIdx.x * 128;
    const int g0 = PADDED ? (colBase >> 6) * 66 : colBase;

    STAGE_B(lsB[0], 0);
    STAGE_A(lsA[0], 0, 0);

    const int aswz = (lk ^ ((lr >> 1) & 3)) << 3;   // (row>>1)&3 == (lr>>1)&3
    int aoff[4];
#pragma unroll
    for (int mf = 0; mf < 4; ++mf)
        aoff[mf] = (mw * 64 + mf * 16 + lr) * 32 + aswz;

    f32x4 acc[4][4] = {};
    for (int kx = 0; kx < NKX; ++kx) {
        const u16* lb = lsB[kx % 3];
#pragma unroll
        for (int t = 0; t < NT; ++t) {
            const int s = kx * NT + t;
            const bool lastS = (kx == NKX - 1) && (t == NT - 1);
            const bool stgB = (t == 0) && (kx + 1 < NKX);
            if (stgB) STAGE_B(lsB[(kx + 1) % 3], kx + 1);
            if (!lastS) {
                const int t1 = (t + 1 == NT) ? 0 : t + 1;
                const int kx1 = (t + 1 == NT) ? kx + 1 : kx;
                STAGE_A(lsA[(s + 1) % 3], t1, kx1);
            }
            // counted wait: N = loads issued THIS phase (min over threads)
            if (lastS) { VMCNT(0); }
            else if (stgB) { if constexpr (MINB == 2) VMCNT(4); else VMCNT(6); }
            else { VMCNT(2); }
            __builtin_amdgcn_s_barrier();
            asm volatile("" ::: "memory");

            const u16* la = lsA[s % 3];
            bf16x8 af[4], bfr[4];
#pragma unroll
            for (int mf = 0; mf < 4; ++mf)
                af[mf] = *(const bf16x8*)(la + aoff[mf]);
            int rb;
            if (PADDED) {
                int dh = t / 3 - 1, dw = t - (t / 3) * 3 - 1;
                rb = (nw + dh + 1) * 66 + dw + 1 + lr;
            } else {
                rb = nw * 64 + lr;
            }
            const int bswz = (lk ^ ((rb >> 1) & 3)) << 3;  // +16 preserves (r>>1)&3
#pragma unroll
            for (int nf = 0; nf < 4; ++nf)
                bfr[nf] = *(const bf16x8*)(lb + (rb + nf * 16) * 32 + bswz);
#pragma unroll
            for (int mf = 0; mf < 4; ++mf)
#pragma unroll
                for (int nf = 0; nf < 4; ++nf)
                    acc[mf][nf] = __builtin_amdgcn_mfma_f32_16x16x32_bf16(
                        af[mf], bfr[nf], acc[mf][nf], 0, 0, 0);
        }
    }

#pragma unroll
    for (int mf = 0; mf < 4; ++mf) {
#pragma unroll
        for (int reg = 0; reg < 4; ++reg) {
            int co = rowBase + mw * 64 + mf * 16 + lk * 4 + reg;
            float sc = scale[co], sh = shift[co];
#pragma unroll
            for (int nf = 0; nf < 4; ++nf) {
                int col = colBase + nw * 64 + nf * 16 + lr;
                float y = acc[mf][nf][reg] * sc + sh;
                if (silu) y = y / (1.f + expf(-y));
                Cn[(long)co * 4096 + col] = y;
            }
        }
    }
}

// ---------------- prep kernels ----------------
__global__ __launch_bounds__(256) void prep_w_kernel(
    const float* __restrict__ w_conv, const float* __restrict__ w_up,
    const float* __restrict__ w_enc,
    u16* __restrict__ wT, u16* __restrict__ wupT, u16* __restrict__ wencT)
{
    int gid = blockIdx.x * 256 + threadIdx.x;
    if (gid < 589824) {             // wT[t][co][ci] = w_conv[co][ci][t]
        int t = gid >> 16;
        int co = (gid >> 8) & 255;
        int ci = gid & 255;
        wT[gid] = f2bf(w_conv[(co * 256 + ci) * 9 + t]);
    }
    if (gid < 131072) wupT[gid] = f2bf(w_up[gid]);
    if (gid < 73728) {              // wencT[t][co<64][ci] (zeros co>=36)
        int t = gid >> 13;
        int co = (gid >> 7) & 63;
        int ci = gid & 127;
        wencT[gid] = (co < 36) ? f2bf(w_enc[(co * 128 + ci) * 9 + t]) : (u16)0;
    }
}

__global__ void prep_bn_kernel(const float* __restrict__ bn_conv,
                               const float* __restrict__ b_up, float* __restrict__ bnp)
{
    int i = threadIdx.x;            // 256
    float g = bn_conv[i], b = bn_conv[256 + i], m = bn_conv[512 + i], v = bn_conv[768 + i];
    float sc = g * rsqrtf(v + EPS);
    bnp[i] = sc;
    bnp[256 + i] = b - m * sc;
    bnp[512 + i] = 1.f;
    bnp[768 + i] = b_up[i];
}

extern "C" void kernel_launch(void* const* d_in, const int* in_sizes, int n_in,
                              void* d_out, int out_size, void* d_ws, size_t ws_size,
                              hipStream_t stream)
{
    const float* input1 = (const float*)d_in[0];
    const float* input2 = (const float*)d_in[1];
    const float* w_down = (const float*)d_in[2];
    const float* b_down = (const float*)d_in[3];
    const float* w_enc  = (const float*)d_in[4];
    const float* b_enc  = (const float*)d_in[5];
    const float* w_up   = (const float*)d_in[6];
    const float* b_up   = (const float*)d_in[7];
    const float* w_l1   = (const float*)d_in[8];
    const float* bn_l1  = (const float*)d_in[9];
    const float* w_l2   = (const float*)d_in[10];
    const float* bn_l2  = (const float*)d_in[11];
    const float* w_wl   = (const float*)d_in[12];
    const float* b_wl   = (const float*)d_in[13];
    const float* w_conv = (const float*)d_in[14];
    const float* bn_conv= (const float*)d_in[15];
    float* out = (float*)d_out;

    // workspace layout (float units). ~74 MB total (aliased).
    float* ws     = (float*)d_ws;
    float* ktTf   = ws;                      //   591,872 f : ktT bf16 [n][1156][128]
    float* wencTf = ktTf + 591872;           //    36,864 f
    float* kt2    = wencTf + 36864;          //   294,912 f
    float* maskb  = kt2 + 294912;            //   294,912 f
    float* hireb  = maskb + 294912;          // 8,388,608 f : hires bf16 -> later u fp32
    float* btb    = hireb + 8388608;         // 8,388,608 f : hiresT bf16 -> later fusedT bf16
    float* wTf    = btb + 8388608;           //   294,912 f
    float* wupTf  = wTf + 294912;            //    65,536 f
    float* bnp    = wupTf + 65536;           //     1,024 f
    u16* ktT      = (u16*)ktTf;
    u16* wencT    = (u16*)wencTf;
    u16* hires_bf = (u16*)hireb;             // dead after transpose
    float* u      = hireb;                   // fp32 u overlays hires after K4b
    u16* bt       = (u16*)btb;               // hiresT; dead after K5
    u16* ftb      = (u16*)btb;               // fusedT overlays hiresT after K5
    u16* wT       = (u16*)wTf;
    u16* wupT     = (u16*)wupTf;

    // prep (independent of data pipeline)
    prep_w_kernel<<<dim3(2304), 256, 0, stream>>>(w_conv, w_up, w_enc, wT, wupT, wencT);
    prep_bn_kernel<<<dim3(1), 256, 0, stream>>>(bn_conv, b_up, bnp);

    // K1: ktT = bf16T(w_down @ input2 + b_down), padded 34x34 grid
    hipMemsetAsync(ktT, 0, 8L * 1156 * 128 * 2, stream);
    down_gemm_kernel<<<dim3(16, 2, 8), 256, 0, stream>>>(w_down, input2, b_down, ktT);
    // K2: kt2 = 9-tap shifted MFMA GEMM
    enc_mfma_kernel<<<dim3(64, 8), 64, 0, stream>>>(wencT, ktT, b_enc, kt2);
    // K3
    mask_softmax_kernel<<<dim3(128), 256, 0, stream>>>(kt2, maskb);
    // K4: CARAFE -> hires bf16 [ci][p]
    carafe_kernel<<<dim3(16384), 256, 0, stream>>>(input2, maskb, hires_bf);
    // K4b: transpose -> hiresT bf16 [p][512]
    transpose_kernel<<<dim3(128, 8), 256, 0, stream>>>(hires_bf, bt);
    // K5: u = w_up @ hiresT + b_up (m97+T4)
    gemm_m97_kernel<512, 1, false><<<dim3(32, 2, 8), 256, 0, stream>>>(
        wupT, bt, bnp + 512, bnp + 768, u, 4096L * 512, 256L * 4096, 0);
    // K6: merged level-attention + blend + transpose -> fusedT (overlays hiresT)
    border_zero_kernel<<<dim3(260), 256, 0, stream>>>(ftb);
    fuse_blend_kernel<<<dim3(128, 8), 256, 0, stream>>>(
        input1, u, w_l1, bn_l1, w_l2, bn_l2, w_wl, b_wl, ftb);
    // K7: final conv (m97+T4, 9-tap) + BN + SiLU
    gemm_m97_kernel<256, 9, true><<<dim3(32, 2, 8), 256, 0, stream>>>(
        wT, ftb, bnp, bnp + 256, out, 4356L * 256, 256L * 4096, 1);
}